// Round 3
// baseline (3193.622 us; speedup 1.0000x reference)
//
#include <hip/hip_runtime.h>
#include <hip/hip_bf16.h>
#include <cstdint>

#define DIMX   128
#define N_REL  6
#define N_BASES 30
#define N_HERB 5000
#define NWIDE  896   // 6 rel blocks + root block
#define YW     768   // y row width (rel blocks only)
#define KSC    512   // scorer feat dim
#define BN     64
#define KT     16

// ---------------- counting / prep ----------------

__global__ void k_count(const int* __restrict__ ei, const int* __restrict__ et,
                        int E, int* __restrict__ cnt) {
    int e = blockIdx.x * blockDim.x + threadIdx.x;
    if (e >= E) return;
    int dst = ei[E + e];
    int t   = et[e];
    atomicAdd(&cnt[dst * N_REL + t], 1);
}

__global__ void k_invcnt(const int* __restrict__ cnt, float* __restrict__ inv, int n) {
    int i = blockIdx.x * blockDim.x + threadIdx.x;
    if (i >= n) return;
    int c = cnt[i];
    inv[i] = 1.0f / (float)(c > 0 ? c : 1);
}

// Wall[d][r*128+o]: columns r*128+o hold W_r[d][o] = sum_b comp[r,b]*basis[b,d,o];
// columns 768+o hold root[d][o].  Layout [128][896] so the wide GEMM reads rows.
__global__ void k_buildW(const float* __restrict__ basis, const float* __restrict__ comp,
                         const float* __restrict__ root, float* __restrict__ Wall) {
    int d = blockIdx.x;          // 0..127
    int r = blockIdx.y;          // 0..6
    int o = threadIdx.x;         // 0..127
    float v;
    if (r < N_REL) {
        float acc = 0.f;
        #pragma unroll
        for (int b = 0; b < N_BASES; ++b)
            acc += comp[r * N_BASES + b] * basis[((size_t)b * DIMX + d) * DIMX + o];
        v = acc;
    } else {
        v = root[(size_t)d * DIMX + o];
    }
    Wall[(size_t)d * NWIDE + r * DIMX + o] = v;
}

// ---------------- wide node GEMM: [M,128] @ [128,896] ----------------
// cb = blockIdx.y (0..6). cb<6: y[n][cb*128+o] = x[n] . W_cb[:,o]
// cb==6: outbuf[n][o] = x[n] . root[:,o] + bias[o]   (accumulator init)
// reluA: apply relu to A on load (layer 2 reads layer-1 pre-activation).

__global__ __launch_bounds__(256)
void k_gemm_wide(const float* __restrict__ x, const float* __restrict__ Wall,
                 const float* __restrict__ bias, float* __restrict__ y,
                 float* __restrict__ outbuf, int nTotal, int reluA) {
    __shared__ float As[BN][DIMX];   // full K tile: 32 KB
    __shared__ float Ws[KT][DIMX];   // 8 KB
    int tid = threadIdx.x;
    int n0 = blockIdx.x * BN;
    int cb = blockIdx.y;

    // stage full A tile [64][128] once
    #pragma unroll
    for (int i = 0; i < 8; ++i) {
        int idx = i * 256 + tid;          // 0..2047 float4 slots
        int row = idx >> 5;               // 0..63
        int c4  = (idx & 31) * 4;
        int ng = n0 + row; if (ng >= nTotal) ng = nTotal - 1;
        float4 av = *(const float4*)(x + (size_t)ng * DIMX + c4);
        if (reluA) {
            av.x = fmaxf(av.x, 0.f); av.y = fmaxf(av.y, 0.f);
            av.z = fmaxf(av.z, 0.f); av.w = fmaxf(av.w, 0.f);
        }
        *(float4*)&As[row][c4] = av;
    }

    int oc = (tid & 31) * 4;         // output col within 128-block
    int nb = (tid >> 5) * 8;         // node base within tile

    float acc[8][4];
    #pragma unroll
    for (int i = 0; i < 8; ++i)
        #pragma unroll
        for (int j = 0; j < 4; ++j) acc[i][j] = 0.f;

    for (int k0 = 0; k0 < DIMX; k0 += KT) {
        __syncthreads();
        // stage Ws[16][128] from Wall rows k0..k0+15, col block cb
        #pragma unroll
        for (int i = 0; i < 2; ++i) {
            int idx = i * 256 + tid;      // 0..511 float4 slots
            int kr = idx >> 5;            // 0..15
            int c4 = (idx & 31) * 4;
            *(float4*)&Ws[kr][c4] =
                *(const float4*)(Wall + (size_t)(k0 + kr) * NWIDE + cb * DIMX + c4);
        }
        __syncthreads();

        #pragma unroll
        for (int kk = 0; kk < KT; kk += 4) {
            float4 wv0 = *(float4*)&Ws[kk + 0][oc];
            float4 wv1 = *(float4*)&Ws[kk + 1][oc];
            float4 wv2 = *(float4*)&Ws[kk + 2][oc];
            float4 wv3 = *(float4*)&Ws[kk + 3][oc];
            #pragma unroll
            for (int i = 0; i < 8; ++i) {
                float4 a4 = *(float4*)&As[nb + i][k0 + kk];
                acc[i][0] += a4.x * wv0.x + a4.y * wv1.x + a4.z * wv2.x + a4.w * wv3.x;
                acc[i][1] += a4.x * wv0.y + a4.y * wv1.y + a4.z * wv2.y + a4.w * wv3.y;
                acc[i][2] += a4.x * wv0.z + a4.y * wv1.z + a4.z * wv2.z + a4.w * wv3.z;
                acc[i][3] += a4.x * wv0.w + a4.y * wv1.w + a4.z * wv2.w + a4.w * wv3.w;
            }
        }
    }

    if (cb < N_REL) {
        #pragma unroll
        for (int i = 0; i < 8; ++i) {
            int n = n0 + nb + i;
            if (n < nTotal) {
                float4 r = { acc[i][0], acc[i][1], acc[i][2], acc[i][3] };
                *(float4*)(y + (size_t)n * YW + cb * DIMX + oc) = r;
            }
        }
    } else {
        float4 bv = *(const float4*)(bias + oc);
        #pragma unroll
        for (int i = 0; i < 8; ++i) {
            int n = n0 + nb + i;
            if (n < nTotal) {
                float4 r = { acc[i][0] + bv.x, acc[i][1] + bv.y,
                             acc[i][2] + bv.z, acc[i][3] + bv.w };
                *(float4*)(outbuf + (size_t)n * DIMX + oc) = r;
            }
        }
    }
}

// ---------------- edge scatter: outbuf[dst] += y[src, rel*128:] * invc[dst,rel] ----
// 32 threads per edge, float4 each, 4 scalar f32 HW atomics into a 30 MB buffer.

__global__ __launch_bounds__(256)
void k_scatter_y(const int* __restrict__ ei, const int* __restrict__ et,
                 const float* __restrict__ y, const float* __restrict__ invc,
                 float* __restrict__ outbuf, int E) {
    unsigned gid = blockIdx.x * blockDim.x + threadIdx.x;
    int e = (int)(gid >> 5);
    if (e >= E) return;
    int q = (int)(gid & 31);
    int src = ei[e];
    int dst = ei[E + e];
    int t   = et[e];
    float s = invc[dst * N_REL + t];
    float4 v = *(const float4*)(y + (size_t)src * YW + t * DIMX + q * 4);
    float* base = outbuf + (size_t)dst * DIMX + q * 4;
    unsafeAtomicAdd(base + 0, v.x * s);
    unsafeAtomicAdd(base + 1, v.y * s);
    unsafeAtomicAdd(base + 2, v.z * s);
    unsafeAtomicAdd(base + 3, v.w * s);
}

// ---------------- scorer GEMM: hid = relu(feat @ sw1 + sb1) ----------------

__global__ __launch_bounds__(256)
void k_scorer_gemm(const float* __restrict__ x2, const int* __restrict__ h_idx,
                   const int* __restrict__ p_idx, const float* __restrict__ sw1,
                   const float* __restrict__ sb1, float* __restrict__ hid, int P) {
    __shared__ float As[BN][KT];
    __shared__ float Ws[KT][DIMX];
    int tid = threadIdx.x;
    int n0 = blockIdx.x * BN;

    int lrow = tid >> 2;
    int lk4  = (tid & 3) * 4;
    int ng = n0 + lrow; if (ng >= P) ng = P - 1;
    int hrow = h_idx[ng];
    int prow = N_HERB + p_idx[ng];

    int oc = (tid & 31) * 4;
    int nb = (tid >> 5) * 8;

    float acc[8][4];
    #pragma unroll
    for (int i = 0; i < 8; ++i)
        #pragma unroll
        for (int j = 0; j < 4; ++j) acc[i][j] = 0.f;

    for (int k0 = 0; k0 < KSC; k0 += KT) {
        int k = k0 + lk4;
        int q = k >> 7;
        int d = k & 127;
        float4 hv = *(const float4*)(x2 + (size_t)hrow * DIMX + d);
        float4 pv = *(const float4*)(x2 + (size_t)prow * DIMX + d);
        float4 av;
        if (q == 0)      av = hv;
        else if (q == 1) av = pv;
        else if (q == 2) { av.x = hv.x * pv.x; av.y = hv.y * pv.y;
                           av.z = hv.z * pv.z; av.w = hv.w * pv.w; }
        else             { av.x = fabsf(hv.x - pv.x); av.y = fabsf(hv.y - pv.y);
                           av.z = fabsf(hv.z - pv.z); av.w = fabsf(hv.w - pv.w); }
        *(float4*)&As[lrow][lk4] = av;

        const float4* wsrc = (const float4*)(sw1 + (size_t)k0 * DIMX);
        ((float4*)Ws)[tid]       = wsrc[tid];
        ((float4*)Ws)[tid + 256] = wsrc[tid + 256];
        __syncthreads();

        #pragma unroll
        for (int kk = 0; kk < KT; kk += 4) {
            float4 wv0 = *(float4*)&Ws[kk + 0][oc];
            float4 wv1 = *(float4*)&Ws[kk + 1][oc];
            float4 wv2 = *(float4*)&Ws[kk + 2][oc];
            float4 wv3 = *(float4*)&Ws[kk + 3][oc];
            #pragma unroll
            for (int i = 0; i < 8; ++i) {
                float4 a4 = *(float4*)&As[nb + i][kk];
                acc[i][0] += a4.x * wv0.x + a4.y * wv1.x + a4.z * wv2.x + a4.w * wv3.x;
                acc[i][1] += a4.x * wv0.y + a4.y * wv1.y + a4.z * wv2.y + a4.w * wv3.y;
                acc[i][2] += a4.x * wv0.z + a4.y * wv1.z + a4.z * wv2.z + a4.w * wv3.z;
                acc[i][3] += a4.x * wv0.w + a4.y * wv1.w + a4.z * wv2.w + a4.w * wv3.w;
            }
        }
        __syncthreads();
    }

    float4 bv = *(const float4*)(sb1 + oc);
    #pragma unroll
    for (int i = 0; i < 8; ++i) {
        int n = n0 + nb + i;
        if (n < P) {
            float4 r;
            r.x = fmaxf(acc[i][0] + bv.x, 0.f);
            r.y = fmaxf(acc[i][1] + bv.y, 0.f);
            r.z = fmaxf(acc[i][2] + bv.z, 0.f);
            r.w = fmaxf(acc[i][3] + bv.w, 0.f);
            *(float4*)(hid + (size_t)n * DIMX + oc) = r;
        }
    }
}

// ---------------- scorer final dot: out = hid @ sw2 + sb2 ----------------

__global__ void k_scorer_out(const float* __restrict__ hid, const float* __restrict__ sw2,
                             const float* __restrict__ sb2, float* __restrict__ out, int P) {
    int tid = blockIdx.x * blockDim.x + threadIdx.x;
    int wave = tid >> 6;
    int lane = tid & 63;
    int half = lane >> 5, l32 = lane & 31;
    int pair = wave * 2 + half;
    if (pair >= P) return;
    float4 hv = *(const float4*)(hid + (size_t)pair * DIMX + l32 * 4);
    float4 wv = *(const float4*)(sw2 + l32 * 4);
    float s = hv.x * wv.x + hv.y * wv.y + hv.z * wv.z + hv.w * wv.w;
    #pragma unroll
    for (int off = 16; off; off >>= 1) s += __shfl_xor(s, off, 64);
    if (l32 == 0) out[pair] = s + sb2[0];
}

// ---------------- launcher ----------------

extern "C" void kernel_launch(void* const* d_in, const int* in_sizes, int n_in,
                              void* d_out, int out_size, void* d_ws, size_t ws_size,
                              hipStream_t stream) {
    const int*   ei       = (const int*)d_in[0];
    const int*   et       = (const int*)d_in[1];
    const int*   h_idx    = (const int*)d_in[2];
    const int*   p_idx    = (const int*)d_in[3];
    const float* node_emb = (const float*)d_in[4];
    const float* basis1   = (const float*)d_in[5];
    const float* comp1    = (const float*)d_in[6];
    const float* root1    = (const float*)d_in[7];
    const float* bias1    = (const float*)d_in[8];
    const float* basis2   = (const float*)d_in[9];
    const float* comp2    = (const float*)d_in[10];
    const float* root2    = (const float*)d_in[11];
    const float* bias2    = (const float*)d_in[12];
    const float* sw1      = (const float*)d_in[13];
    const float* sb1      = (const float*)d_in[14];
    const float* sw2      = (const float*)d_in[15];
    const float* sb2      = (const float*)d_in[16];
    float* out = (float*)d_out;

    int E  = in_sizes[1];
    int P  = in_sizes[2];
    int NN = in_sizes[4] / DIMX;   // 60000

    // workspace layout (floats)
    float* y    = (float*)d_ws;                                   // NN*768 (184 MB)
    float* hid  = y;                                              // alias (scorer phase only)
    int*   cnt  = (int*)(y + (size_t)NN * YW);                    // NN*6
    float* invc = (float*)(cnt + (size_t)NN * N_REL);             // NN*6
    float* out1 = invc + (size_t)NN * N_REL;                      // NN*128
    float* out2 = out1 + (size_t)NN * DIMX;                       // NN*128
    float* Wall = out2 + (size_t)NN * DIMX;                       // 128*896

    hipMemsetAsync(cnt, 0, (size_t)NN * N_REL * sizeof(int), stream);
    k_count<<<(E + 255) / 256, 256, 0, stream>>>(ei, et, E, cnt);
    k_invcnt<<<(NN * N_REL + 255) / 256, 256, 0, stream>>>(cnt, invc, NN * N_REL);

    dim3 gemmGrid((NN + BN - 1) / BN, N_REL + 1);
    dim3 wGrid(DIMX, N_REL + 1);

    // layer 1: y = emb @ [W1..W6]; out1 = emb @ root1 + bias1; scatter adds means
    k_buildW<<<wGrid, DIMX, 0, stream>>>(basis1, comp1, root1, Wall);
    k_gemm_wide<<<gemmGrid, 256, 0, stream>>>(node_emb, Wall, bias1, y, out1, NN, 0);
    k_scatter_y<<<((size_t)E * 32 + 255) / 256, 256, 0, stream>>>(ei, et, y, invc, out1, E);

    // layer 2: A = relu(out1) applied on load
    k_buildW<<<wGrid, DIMX, 0, stream>>>(basis2, comp2, root2, Wall);
    k_gemm_wide<<<gemmGrid, 256, 0, stream>>>(out1, Wall, bias2, y, out2, NN, 1);
    k_scatter_y<<<((size_t)E * 32 + 255) / 256, 256, 0, stream>>>(ei, et, y, invc, out2, E);

    // scorer (x2 = out2; herbs at rows [0,5000), proteins at 5000+p)
    k_scorer_gemm<<<(P + BN - 1) / BN, 256, 0, stream>>>(out2, h_idx, p_idx, sw1, sb1, hid, P);
    k_scorer_out<<<((size_t)P * 32 + 255) / 256, 256, 0, stream>>>(hid, sw2, sb2, out, P);
}

// Round 4
// 1317.299 us; speedup vs baseline: 2.4244x; 2.4244x over previous
//
#include <hip/hip_runtime.h>
#include <hip/hip_bf16.h>
#include <cstdint>

#define DIMX   128
#define N_REL  6
#define N_BASES 30
#define N_HERB 5000
#define NWIDE  896   // 6 rel blocks + root block
#define YW     768   // y row width (rel blocks only)
#define KSC    512   // scorer feat dim
#define BN     64
#define KT     16

// ---------------- counting / prep ----------------

__global__ void k_count(const int* __restrict__ ei, const int* __restrict__ et,
                        int E, int* __restrict__ cnt) {
    int e = blockIdx.x * blockDim.x + threadIdx.x;
    if (e >= E) return;
    int dst = ei[E + e];
    int t   = et[e];
    atomicAdd(&cnt[dst * N_REL + t], 1);
}

__global__ void k_invcnt(const int* __restrict__ cnt, float* __restrict__ inv, int n) {
    int i = blockIdx.x * blockDim.x + threadIdx.x;
    if (i >= n) return;
    int c = cnt[i];
    inv[i] = 1.0f / (float)(c > 0 ? c : 1);
}

__global__ void k_deg(const int* __restrict__ cnt, int* __restrict__ deg, int n) {
    int i = blockIdx.x * blockDim.x + threadIdx.x;
    if (i >= n) return;
    int s = 0;
    #pragma unroll
    for (int t = 0; t < N_REL; ++t) s += cnt[i * N_REL + t];
    deg[i] = s;
}

// ---------------- exclusive scan over deg[n] -> rowptr ----------------
// 1024 elems per block (256 thr x 4).

__global__ void k_scan1(const int* __restrict__ deg, int* __restrict__ bsums, int n) {
    __shared__ int ssum[256];
    int tid = threadIdx.x;
    int base = blockIdx.x * 1024;
    int local = 0;
    #pragma unroll
    for (int i = 0; i < 4; ++i) {
        int idx = base + tid * 4 + i;
        local += (idx < n) ? deg[idx] : 0;
    }
    ssum[tid] = local; __syncthreads();
    for (int off = 128; off; off >>= 1) {
        if (tid < off) ssum[tid] += ssum[tid + off];
        __syncthreads();
    }
    if (tid == 0) bsums[blockIdx.x] = ssum[0];
}

__global__ void k_scan2(int* __restrict__ bsums, int nb, int* __restrict__ rowptr, int n) {
    if (threadIdx.x == 0 && blockIdx.x == 0) {
        int run = 0;
        for (int b = 0; b < nb; ++b) { int t = bsums[b]; bsums[b] = run; run += t; }
        rowptr[n] = run;
    }
}

__global__ void k_scan3(const int* __restrict__ deg, const int* __restrict__ bsums,
                        int* __restrict__ rowptr, int n) {
    __shared__ int ssum[256];
    int tid = threadIdx.x;
    int base = blockIdx.x * 1024;
    int idx0 = base + tid * 4;
    int v[4]; int local = 0;
    #pragma unroll
    for (int i = 0; i < 4; ++i) {
        int idx = idx0 + i;
        v[i] = (idx < n) ? deg[idx] : 0;
        local += v[i];
    }
    ssum[tid] = local; __syncthreads();
    for (int off = 1; off < 256; off <<= 1) {
        int t = (tid >= off) ? ssum[tid - off] : 0;
        __syncthreads();
        ssum[tid] += t;
        __syncthreads();
    }
    int excl = ssum[tid] - local + bsums[blockIdx.x];
    #pragma unroll
    for (int i = 0; i < 4; ++i) {
        int idx = idx0 + i;
        if (idx < n) { rowptr[idx] = excl; excl += v[i]; }
    }
}

// ---------------- fill packed CSR edge list ----------------

__global__ void k_fill(const int* __restrict__ ei, const int* __restrict__ et, int E,
                       const int* __restrict__ rowptr, int* __restrict__ fillc,
                       int* __restrict__ pedge) {
    int e = blockIdx.x * blockDim.x + threadIdx.x;
    if (e >= E) return;
    int src = ei[e];
    int dst = ei[E + e];
    int t   = et[e];
    int pos = atomicAdd(&fillc[dst], 1);
    pedge[rowptr[dst] + pos] = (src << 3) | t;
}

// Wall[d][r*128+o]: columns r*128+o hold W_r[d][o] = sum_b comp[r,b]*basis[b,d,o];
// columns 768+o hold root[d][o].
__global__ void k_buildW(const float* __restrict__ basis, const float* __restrict__ comp,
                         const float* __restrict__ root, float* __restrict__ Wall) {
    int d = blockIdx.x;          // 0..127
    int r = blockIdx.y;          // 0..6
    int o = threadIdx.x;         // 0..127
    float v;
    if (r < N_REL) {
        float acc = 0.f;
        #pragma unroll
        for (int b = 0; b < N_BASES; ++b)
            acc += comp[r * N_BASES + b] * basis[((size_t)b * DIMX + d) * DIMX + o];
        v = acc;
    } else {
        v = root[(size_t)d * DIMX + o];
    }
    Wall[(size_t)d * NWIDE + r * DIMX + o] = v;
}

// ---------------- wide node GEMM: [M,128] @ [128,896] ----------------
// cb<6: y[n][cb*128+o] = x[n].W_cb[:,o];  cb==6: outbuf[n][o] = x[n].root + bias.

__global__ __launch_bounds__(256)
void k_gemm_wide(const float* __restrict__ x, const float* __restrict__ Wall,
                 const float* __restrict__ bias, float* __restrict__ y,
                 float* __restrict__ outbuf, int nTotal, int reluA) {
    __shared__ float As[BN][DIMX];   // 32 KB
    __shared__ float Ws[KT][DIMX];   // 8 KB
    int tid = threadIdx.x;
    int n0 = blockIdx.x * BN;
    int cb = blockIdx.y;

    #pragma unroll
    for (int i = 0; i < 8; ++i) {
        int idx = i * 256 + tid;
        int row = idx >> 5;
        int c4  = (idx & 31) * 4;
        int ng = n0 + row; if (ng >= nTotal) ng = nTotal - 1;
        float4 av = *(const float4*)(x + (size_t)ng * DIMX + c4);
        if (reluA) {
            av.x = fmaxf(av.x, 0.f); av.y = fmaxf(av.y, 0.f);
            av.z = fmaxf(av.z, 0.f); av.w = fmaxf(av.w, 0.f);
        }
        *(float4*)&As[row][c4] = av;
    }

    int oc = (tid & 31) * 4;
    int nb = (tid >> 5) * 8;

    float acc[8][4];
    #pragma unroll
    for (int i = 0; i < 8; ++i)
        #pragma unroll
        for (int j = 0; j < 4; ++j) acc[i][j] = 0.f;

    for (int k0 = 0; k0 < DIMX; k0 += KT) {
        __syncthreads();
        #pragma unroll
        for (int i = 0; i < 2; ++i) {
            int idx = i * 256 + tid;
            int kr = idx >> 5;
            int c4 = (idx & 31) * 4;
            *(float4*)&Ws[kr][c4] =
                *(const float4*)(Wall + (size_t)(k0 + kr) * NWIDE + cb * DIMX + c4);
        }
        __syncthreads();

        #pragma unroll
        for (int kk = 0; kk < KT; kk += 4) {
            float4 wv0 = *(float4*)&Ws[kk + 0][oc];
            float4 wv1 = *(float4*)&Ws[kk + 1][oc];
            float4 wv2 = *(float4*)&Ws[kk + 2][oc];
            float4 wv3 = *(float4*)&Ws[kk + 3][oc];
            #pragma unroll
            for (int i = 0; i < 8; ++i) {
                float4 a4 = *(float4*)&As[nb + i][k0 + kk];
                acc[i][0] += a4.x * wv0.x + a4.y * wv1.x + a4.z * wv2.x + a4.w * wv3.x;
                acc[i][1] += a4.x * wv0.y + a4.y * wv1.y + a4.z * wv2.y + a4.w * wv3.y;
                acc[i][2] += a4.x * wv0.z + a4.y * wv1.z + a4.z * wv2.z + a4.w * wv3.z;
                acc[i][3] += a4.x * wv0.w + a4.y * wv1.w + a4.z * wv2.w + a4.w * wv3.w;
            }
        }
    }

    if (cb < N_REL) {
        #pragma unroll
        for (int i = 0; i < 8; ++i) {
            int n = n0 + nb + i;
            if (n < nTotal) {
                float4 r = { acc[i][0], acc[i][1], acc[i][2], acc[i][3] };
                *(float4*)(y + (size_t)n * YW + cb * DIMX + oc) = r;
            }
        }
    } else {
        float4 bv = *(const float4*)(bias + oc);
        #pragma unroll
        for (int i = 0; i < 8; ++i) {
            int n = n0 + nb + i;
            if (n < nTotal) {
                float4 r = { acc[i][0] + bv.x, acc[i][1] + bv.y,
                             acc[i][2] + bv.z, acc[i][3] + bv.w };
                *(float4*)(outbuf + (size_t)n * DIMX + oc) = r;
            }
        }
    }
}

// ---------------- CSR gather: outbuf[dst] += sum_e y[src_e, t_e*128:] * invc[dst,t_e] ----
// One wave per dst; lane handles float2 (512B/edge coalesced). No atomics.

__global__ __launch_bounds__(256)
void k_gather(const int* __restrict__ pedge, const int* __restrict__ rowptr,
              const float* __restrict__ invc, const float* __restrict__ y,
              float* __restrict__ outbuf, int NN) {
    int wid = (blockIdx.x * blockDim.x + threadIdx.x) >> 6;
    if (wid >= NN) return;
    int lane = threadIdx.x & 63;
    int dst = wid;
    int j0 = rowptr[dst], j1 = rowptr[dst + 1];

    float* op = outbuf + (size_t)dst * DIMX + lane * 2;
    float2 acc = *(float2*)op;

    int j = j0;
    for (; j + 1 < j1; j += 2) {
        int pa = pedge[j], pb = pedge[j + 1];
        int ta = pa & 7, tb = pb & 7;
        int sa = pa >> 3, sb = pb >> 3;
        float fa = invc[dst * N_REL + ta];
        float fb = invc[dst * N_REL + tb];
        float2 va = *(const float2*)(y + (size_t)sa * YW + ta * DIMX + lane * 2);
        float2 vb = *(const float2*)(y + (size_t)sb * YW + tb * DIMX + lane * 2);
        acc.x += va.x * fa + vb.x * fb;
        acc.y += va.y * fa + vb.y * fb;
    }
    if (j < j1) {
        int pa = pedge[j];
        int ta = pa & 7;
        int sa = pa >> 3;
        float fa = invc[dst * N_REL + ta];
        float2 va = *(const float2*)(y + (size_t)sa * YW + ta * DIMX + lane * 2);
        acc.x += va.x * fa;
        acc.y += va.y * fa;
    }
    *(float2*)op = acc;
}

// ---------------- scorer GEMM: hid = relu(feat @ sw1 + sb1) ----------------

__global__ __launch_bounds__(256)
void k_scorer_gemm(const float* __restrict__ x2, const int* __restrict__ h_idx,
                   const int* __restrict__ p_idx, const float* __restrict__ sw1,
                   const float* __restrict__ sb1, float* __restrict__ hid, int P) {
    __shared__ float As[BN][KT];
    __shared__ float Ws[KT][DIMX];
    int tid = threadIdx.x;
    int n0 = blockIdx.x * BN;

    int lrow = tid >> 2;
    int lk4  = (tid & 3) * 4;
    int ng = n0 + lrow; if (ng >= P) ng = P - 1;
    int hrow = h_idx[ng];
    int prow = N_HERB + p_idx[ng];

    int oc = (tid & 31) * 4;
    int nb = (tid >> 5) * 8;

    float acc[8][4];
    #pragma unroll
    for (int i = 0; i < 8; ++i)
        #pragma unroll
        for (int j = 0; j < 4; ++j) acc[i][j] = 0.f;

    for (int k0 = 0; k0 < KSC; k0 += KT) {
        int k = k0 + lk4;
        int q = k >> 7;
        int d = k & 127;
        float4 hv = *(const float4*)(x2 + (size_t)hrow * DIMX + d);
        float4 pv = *(const float4*)(x2 + (size_t)prow * DIMX + d);
        float4 av;
        if (q == 0)      av = hv;
        else if (q == 1) av = pv;
        else if (q == 2) { av.x = hv.x * pv.x; av.y = hv.y * pv.y;
                           av.z = hv.z * pv.z; av.w = hv.w * pv.w; }
        else             { av.x = fabsf(hv.x - pv.x); av.y = fabsf(hv.y - pv.y);
                           av.z = fabsf(hv.z - pv.z); av.w = fabsf(hv.w - pv.w); }
        *(float4*)&As[lrow][lk4] = av;

        const float4* wsrc = (const float4*)(sw1 + (size_t)k0 * DIMX);
        ((float4*)Ws)[tid]       = wsrc[tid];
        ((float4*)Ws)[tid + 256] = wsrc[tid + 256];
        __syncthreads();

        #pragma unroll
        for (int kk = 0; kk < KT; kk += 4) {
            float4 wv0 = *(float4*)&Ws[kk + 0][oc];
            float4 wv1 = *(float4*)&Ws[kk + 1][oc];
            float4 wv2 = *(float4*)&Ws[kk + 2][oc];
            float4 wv3 = *(float4*)&Ws[kk + 3][oc];
            #pragma unroll
            for (int i = 0; i < 8; ++i) {
                float4 a4 = *(float4*)&As[nb + i][kk];
                acc[i][0] += a4.x * wv0.x + a4.y * wv1.x + a4.z * wv2.x + a4.w * wv3.x;
                acc[i][1] += a4.x * wv0.y + a4.y * wv1.y + a4.z * wv2.y + a4.w * wv3.y;
                acc[i][2] += a4.x * wv0.z + a4.y * wv1.z + a4.z * wv2.z + a4.w * wv3.z;
                acc[i][3] += a4.x * wv0.w + a4.y * wv1.w + a4.z * wv2.w + a4.w * wv3.w;
            }
        }
        __syncthreads();
    }

    float4 bv = *(const float4*)(sb1 + oc);
    #pragma unroll
    for (int i = 0; i < 8; ++i) {
        int n = n0 + nb + i;
        if (n < P) {
            float4 r;
            r.x = fmaxf(acc[i][0] + bv.x, 0.f);
            r.y = fmaxf(acc[i][1] + bv.y, 0.f);
            r.z = fmaxf(acc[i][2] + bv.z, 0.f);
            r.w = fmaxf(acc[i][3] + bv.w, 0.f);
            *(float4*)(hid + (size_t)n * DIMX + oc) = r;
        }
    }
}

// ---------------- scorer final dot: out = hid @ sw2 + sb2 ----------------

__global__ void k_scorer_out(const float* __restrict__ hid, const float* __restrict__ sw2,
                             const float* __restrict__ sb2, float* __restrict__ out, int P) {
    int tid = blockIdx.x * blockDim.x + threadIdx.x;
    int wave = tid >> 6;
    int lane = tid & 63;
    int half = lane >> 5, l32 = lane & 31;
    int pair = wave * 2 + half;
    if (pair >= P) return;
    float4 hv = *(const float4*)(hid + (size_t)pair * DIMX + l32 * 4);
    float4 wv = *(const float4*)(sw2 + l32 * 4);
    float s = hv.x * wv.x + hv.y * wv.y + hv.z * wv.z + hv.w * wv.w;
    #pragma unroll
    for (int off = 16; off; off >>= 1) s += __shfl_xor(s, off, 64);
    if (l32 == 0) out[pair] = s + sb2[0];
}

// ---------------- launcher ----------------

extern "C" void kernel_launch(void* const* d_in, const int* in_sizes, int n_in,
                              void* d_out, int out_size, void* d_ws, size_t ws_size,
                              hipStream_t stream) {
    const int*   ei       = (const int*)d_in[0];
    const int*   et       = (const int*)d_in[1];
    const int*   h_idx    = (const int*)d_in[2];
    const int*   p_idx    = (const int*)d_in[3];
    const float* node_emb = (const float*)d_in[4];
    const float* basis1   = (const float*)d_in[5];
    const float* comp1    = (const float*)d_in[6];
    const float* root1    = (const float*)d_in[7];
    const float* bias1    = (const float*)d_in[8];
    const float* basis2   = (const float*)d_in[9];
    const float* comp2    = (const float*)d_in[10];
    const float* root2    = (const float*)d_in[11];
    const float* bias2    = (const float*)d_in[12];
    const float* sw1      = (const float*)d_in[13];
    const float* sb1      = (const float*)d_in[14];
    const float* sw2      = (const float*)d_in[15];
    const float* sb2      = (const float*)d_in[16];
    float* out = (float*)d_out;

    int E  = in_sizes[1];
    int P  = in_sizes[2];
    int NN = in_sizes[4] / DIMX;   // 60000

    // workspace layout
    float* y      = (float*)d_ws;                                 // NN*768 (184 MB)
    float* hid    = y;                                            // alias (scorer phase)
    int*   cnt    = (int*)(y + (size_t)NN * YW);                  // NN*6
    float* invc   = (float*)(cnt + (size_t)NN * N_REL);           // NN*6
    float* out1   = invc + (size_t)NN * N_REL;                    // NN*128
    float* out2   = out1 + (size_t)NN * DIMX;                     // NN*128
    float* Wall   = out2 + (size_t)NN * DIMX;                     // 128*896
    int*   deg    = (int*)(Wall + (size_t)DIMX * NWIDE);          // NN
    int*   rowptr = deg + NN;                                     // NN+1
    int*   fillc  = rowptr + NN + 1;                              // NN
    int*   bsums  = fillc + NN;                                   // 64
    int*   pedge  = bsums + 64;                                   // E

    int nScanB = (NN + 1023) / 1024;

    hipMemsetAsync(cnt, 0, (size_t)NN * N_REL * sizeof(int), stream);
    hipMemsetAsync(fillc, 0, (size_t)NN * sizeof(int), stream);

    // CSR build (shared by both layers)
    k_count<<<(E + 255) / 256, 256, 0, stream>>>(ei, et, E, cnt);
    k_invcnt<<<(NN * N_REL + 255) / 256, 256, 0, stream>>>(cnt, invc, NN * N_REL);
    k_deg<<<(NN + 255) / 256, 256, 0, stream>>>(cnt, deg, NN);
    k_scan1<<<nScanB, 256, 0, stream>>>(deg, bsums, NN);
    k_scan2<<<1, 64, 0, stream>>>(bsums, nScanB, rowptr, NN);
    k_scan3<<<nScanB, 256, 0, stream>>>(deg, bsums, rowptr, NN);
    k_fill<<<(E + 255) / 256, 256, 0, stream>>>(ei, et, E, rowptr, fillc, pedge);

    dim3 gemmGrid((NN + BN - 1) / BN, N_REL + 1);
    dim3 wGrid(DIMX, N_REL + 1);
    int gatherBlocks = ((size_t)NN * 64 + 255) / 256;

    // layer 1: y = emb @ [W1..W6]; out1 = emb @ root1 + bias1; gather adds means
    k_buildW<<<wGrid, DIMX, 0, stream>>>(basis1, comp1, root1, Wall);
    k_gemm_wide<<<gemmGrid, 256, 0, stream>>>(node_emb, Wall, bias1, y, out1, NN, 0);
    k_gather<<<gatherBlocks, 256, 0, stream>>>(pedge, rowptr, invc, y, out1, NN);

    // layer 2: A = relu(out1) applied on load
    k_buildW<<<wGrid, DIMX, 0, stream>>>(basis2, comp2, root2, Wall);
    k_gemm_wide<<<gemmGrid, 256, 0, stream>>>(out1, Wall, bias2, y, out2, NN, 1);
    k_gather<<<gatherBlocks, 256, 0, stream>>>(pedge, rowptr, invc, y, out2, NN);

    // scorer
    k_scorer_gemm<<<(P + BN - 1) / BN, 256, 0, stream>>>(out2, h_idx, p_idx, sw1, sb1, hid, P);
    k_scorer_out<<<((size_t)P * 32 + 255) / 256, 256, 0, stream>>>(hid, sw2, sb2, out, P);
}

// Round 6
// 903.837 us; speedup vs baseline: 3.5334x; 1.4575x over previous
//
#include <hip/hip_runtime.h>
#include <hip/hip_bf16.h>
#include <cstdint>

#define DIMX   128
#define N_REL  6
#define N_BASES 30
#define N_HERB 5000
#define NWIDE  896   // 6 rel blocks + root block
#define YW     768   // y row width (rel blocks only)
#define KSC    512   // scorer feat dim
#define BN     64
#define KT     16

typedef __attribute__((ext_vector_type(8))) short short8v;
typedef __attribute__((ext_vector_type(4))) float f32x4;

__device__ __forceinline__ unsigned short f2bf_rne(float f) {
    union { float f; unsigned u; } v; v.f = f;
    unsigned u = v.u;
    u += 0x7fffu + ((u >> 16) & 1u);
    return (unsigned short)(u >> 16);
}
__device__ __forceinline__ float bf2f(unsigned short h) {
    union { unsigned u; float f; } v; v.u = ((unsigned)h) << 16;
    return v.f;
}

// ---------------- counting / prep ----------------

__global__ void k_count(const int* __restrict__ ei, const int* __restrict__ et,
                        int E, int* __restrict__ cnt) {
    int e = blockIdx.x * blockDim.x + threadIdx.x;
    if (e >= E) return;
    int dst = ei[E + e];
    int t   = et[e];
    atomicAdd(&cnt[dst * N_REL + t], 1);
}

__global__ void k_invcnt(const int* __restrict__ cnt, float* __restrict__ inv, int n) {
    int i = blockIdx.x * blockDim.x + threadIdx.x;
    if (i >= n) return;
    int c = cnt[i];
    inv[i] = 1.0f / (float)(c > 0 ? c : 1);
}

__global__ void k_deg(const int* __restrict__ cnt, int* __restrict__ deg, int n) {
    int i = blockIdx.x * blockDim.x + threadIdx.x;
    if (i >= n) return;
    int s = 0;
    #pragma unroll
    for (int t = 0; t < N_REL; ++t) s += cnt[i * N_REL + t];
    deg[i] = s;
}

// ---------------- exclusive scan over deg[n] -> rowptr ----------------

__global__ void k_scan1(const int* __restrict__ deg, int* __restrict__ bsums, int n) {
    __shared__ int ssum[256];
    int tid = threadIdx.x;
    int base = blockIdx.x * 1024;
    int local = 0;
    #pragma unroll
    for (int i = 0; i < 4; ++i) {
        int idx = base + tid * 4 + i;
        local += (idx < n) ? deg[idx] : 0;
    }
    ssum[tid] = local; __syncthreads();
    for (int off = 128; off; off >>= 1) {
        if (tid < off) ssum[tid] += ssum[tid + off];
        __syncthreads();
    }
    if (tid == 0) bsums[blockIdx.x] = ssum[0];
}

__global__ void k_scan2(int* __restrict__ bsums, int nb, int* __restrict__ rowptr, int n) {
    if (threadIdx.x == 0 && blockIdx.x == 0) {
        int run = 0;
        for (int b = 0; b < nb; ++b) { int t = bsums[b]; bsums[b] = run; run += t; }
        rowptr[n] = run;
    }
}

__global__ void k_scan3(const int* __restrict__ deg, const int* __restrict__ bsums,
                        int* __restrict__ rowptr, int n) {
    __shared__ int ssum[256];
    int tid = threadIdx.x;
    int base = blockIdx.x * 1024;
    int idx0 = base + tid * 4;
    int v[4]; int local = 0;
    #pragma unroll
    for (int i = 0; i < 4; ++i) {
        int idx = idx0 + i;
        v[i] = (idx < n) ? deg[idx] : 0;
        local += v[i];
    }
    ssum[tid] = local; __syncthreads();
    for (int off = 1; off < 256; off <<= 1) {
        int t = (tid >= off) ? ssum[tid - off] : 0;
        __syncthreads();
        ssum[tid] += t;
        __syncthreads();
    }
    int excl = ssum[tid] - local + bsums[blockIdx.x];
    #pragma unroll
    for (int i = 0; i < 4; ++i) {
        int idx = idx0 + i;
        if (idx < n) { rowptr[idx] = excl; excl += v[i]; }
    }
}

__global__ void k_fill(const int* __restrict__ ei, const int* __restrict__ et, int E,
                       const int* __restrict__ rowptr, int* __restrict__ fillc,
                       int* __restrict__ pedge) {
    int e = blockIdx.x * blockDim.x + threadIdx.x;
    if (e >= E) return;
    int src = ei[e];
    int dst = ei[E + e];
    int t   = et[e];
    int pos = atomicAdd(&fillc[dst], 1);
    pedge[rowptr[dst] + pos] = (src << 3) | t;
}

// ---------------- W2: packed transposed bf16 hi/lo weights ----------------
// W2[og][0..127]=hi(W[k][og]), W2[og][128..255]=lo, og = r*128+o (r=6 -> root).
// Row-major [896][256] ushort so B-fragments are 16B-contiguous per lane.

__global__ void k_buildW2(const float* __restrict__ basis, const float* __restrict__ comp,
                          const float* __restrict__ root, unsigned short* __restrict__ W2) {
    int d = blockIdx.x;          // k index 0..127
    int r = blockIdx.y;          // 0..6
    int o = threadIdx.x;         // 0..127
    float v;
    if (r < N_REL) {
        float acc = 0.f;
        #pragma unroll
        for (int b = 0; b < N_BASES; ++b)
            acc += comp[r * N_BASES + b] * basis[((size_t)b * DIMX + d) * DIMX + o];
        v = acc;
    } else {
        v = root[(size_t)d * DIMX + o];
    }
    unsigned short hi = f2bf_rne(v);
    unsigned short lo = f2bf_rne(v - bf2f(hi));
    size_t og = (size_t)(r * DIMX + o);
    W2[og * 256 + d] = hi;
    W2[og * 256 + 128 + d] = lo;
}

// ---------------- A2 prep: fp32 rows -> packed bf16 {hi[128],lo[128]} ----------------
// Safe in-place (dst may alias src): 16 rows/block, loads before stores, row-local.

__global__ __launch_bounds__(256)
void k_prepA(const float* __restrict__ x, unsigned short* __restrict__ A2,
             int NN, int relu) {
    int row = blockIdx.x * 16 + (threadIdx.x >> 4);
    int c8  = (threadIdx.x & 15) * 8;
    float v[8];
    bool ok = (row < NN);
    if (ok) {
        float4 a = *(const float4*)(x + (size_t)row * DIMX + c8);
        float4 b = *(const float4*)(x + (size_t)row * DIMX + c8 + 4);
        v[0]=a.x; v[1]=a.y; v[2]=a.z; v[3]=a.w;
        v[4]=b.x; v[5]=b.y; v[6]=b.z; v[7]=b.w;
        if (relu) {
            #pragma unroll
            for (int i = 0; i < 8; ++i) v[i] = fmaxf(v[i], 0.f);
        }
    }
    __syncthreads();
    if (ok) {
        unsigned short hi[8], lo[8];
        #pragma unroll
        for (int i = 0; i < 8; ++i) {
            hi[i] = f2bf_rne(v[i]);
            lo[i] = f2bf_rne(v[i] - bf2f(hi[i]));
        }
        unsigned short* base = A2 + (size_t)row * 256;
        *(ulonglong2*)(base + c8)       = *(ulonglong2*)hi;
        *(ulonglong2*)(base + 128 + c8) = *(ulonglong2*)lo;
    }
}

// ---------------- MFMA node GEMM: [M,128] @ [128,896], bf16 hi/lo x3 ----------------
// grid (M/64, 7); 256 thr = 4 waves; wave w: rows m0+16w..+15, 8 N-tiles of 16.
// cb<6: write y[n][cb*128+o]; cb==6: outbuf[n][o] = . + bias[o].

__global__ __launch_bounds__(256)
void k_gemm_mfma(const unsigned short* __restrict__ A2, const unsigned short* __restrict__ W2,
                 const float* __restrict__ bias, float* __restrict__ y,
                 float* __restrict__ outbuf, int NN) {
    int tid = threadIdx.x;
    int w  = tid >> 6;
    int l  = tid & 63;
    int cl = l & 15;
    int kg = (l >> 4) * 8;
    int cb = blockIdx.y;
    int m0 = blockIdx.x * 64 + w * 16;

    int rowA = m0 + cl; if (rowA >= NN) rowA = NN - 1;
    const unsigned short* aBase = A2 + (size_t)rowA * 256 + kg;
    const unsigned short* bBase = W2 + (size_t)(cb * DIMX + cl) * 256 + kg;

    f32x4 acc[8];
    #pragma unroll
    for (int j = 0; j < 8; ++j) acc[j] = (f32x4){0.f, 0.f, 0.f, 0.f};

    #pragma unroll
    for (int k0 = 0; k0 < 128; k0 += 32) {
        short8v ah = *(const short8v*)(aBase + k0);
        short8v al = *(const short8v*)(aBase + 128 + k0);
        #pragma unroll
        for (int j = 0; j < 8; ++j) {
            const unsigned short* bp = bBase + (size_t)j * 16 * 256;
            short8v bh = *(const short8v*)(bp + k0);
            short8v bl = *(const short8v*)(bp + 128 + k0);
            acc[j] = __builtin_amdgcn_mfma_f32_16x16x32_bf16(ah, bh, acc[j], 0, 0, 0);
            acc[j] = __builtin_amdgcn_mfma_f32_16x16x32_bf16(al, bh, acc[j], 0, 0, 0);
            acc[j] = __builtin_amdgcn_mfma_f32_16x16x32_bf16(ah, bl, acc[j], 0, 0, 0);
        }
    }

    int rq = (l >> 4) * 4;   // C/D: col = l&15, row = (l>>4)*4 + reg
    if (cb < N_REL) {
        #pragma unroll
        for (int j = 0; j < 8; ++j) {
            #pragma unroll
            for (int q = 0; q < 4; ++q) {
                int n = m0 + rq + q;
                if (n < NN)
                    y[(size_t)n * YW + cb * DIMX + j * 16 + cl] = acc[j][q];
            }
        }
    } else {
        #pragma unroll
        for (int j = 0; j < 8; ++j) {
            float bv = bias[j * 16 + cl];
            #pragma unroll
            for (int q = 0; q < 4; ++q) {
                int n = m0 + rq + q;
                if (n < NN)
                    outbuf[(size_t)n * DIMX + j * 16 + cl] = acc[j][q] + bv;
            }
        }
    }
}

// ---------------- CSR gather: outbuf[dst] += sum_e y[src_e, t_e*128:] * invc[dst,t_e] ----

__global__ __launch_bounds__(256)
void k_gather(const int* __restrict__ pedge, const int* __restrict__ rowptr,
              const float* __restrict__ invc, const float* __restrict__ y,
              float* __restrict__ outbuf, int NN) {
    int wid = (blockIdx.x * blockDim.x + threadIdx.x) >> 6;
    if (wid >= NN) return;
    int lane = threadIdx.x & 63;
    int dst = wid;
    int j0 = rowptr[dst], j1 = rowptr[dst + 1];

    float* op = outbuf + (size_t)dst * DIMX + lane * 2;
    float2 acc = *(float2*)op;

    int j = j0;
    for (; j + 1 < j1; j += 2) {
        int pa = pedge[j], pb = pedge[j + 1];
        int ta = pa & 7, tb = pb & 7;
        int sa = pa >> 3, sb = pb >> 3;
        float fa = invc[dst * N_REL + ta];
        float fb = invc[dst * N_REL + tb];
        float2 va = *(const float2*)(y + (size_t)sa * YW + ta * DIMX + lane * 2);
        float2 vb = *(const float2*)(y + (size_t)sb * YW + tb * DIMX + lane * 2);
        acc.x += va.x * fa + vb.x * fb;
        acc.y += va.y * fa + vb.y * fb;
    }
    if (j < j1) {
        int pa = pedge[j];
        int ta = pa & 7;
        int sa = pa >> 3;
        float fa = invc[dst * N_REL + ta];
        float2 va = *(const float2*)(y + (size_t)sa * YW + ta * DIMX + lane * 2);
        acc.x += va.x * fa;
        acc.y += va.y * fa;
    }
    *(float2*)op = acc;
}

// ---------------- scorer GEMM: hid = relu(feat @ sw1 + sb1) ----------------

__global__ __launch_bounds__(256)
void k_scorer_gemm(const float* __restrict__ x2, const int* __restrict__ h_idx,
                   const int* __restrict__ p_idx, const float* __restrict__ sw1,
                   const float* __restrict__ sb1, float* __restrict__ hid, int P) {
    __shared__ float As[BN][KT];
    __shared__ float Ws[KT][DIMX];
    int tid = threadIdx.x;
    int n0 = blockIdx.x * BN;

    int lrow = tid >> 2;
    int lk4  = (tid & 3) * 4;
    int ng = n0 + lrow; if (ng >= P) ng = P - 1;
    int hrow = h_idx[ng];
    int prow = N_HERB + p_idx[ng];

    int oc = (tid & 31) * 4;
    int nb = (tid >> 5) * 8;

    float acc[8][4];
    #pragma unroll
    for (int i = 0; i < 8; ++i)
        #pragma unroll
        for (int j = 0; j < 4; ++j) acc[i][j] = 0.f;

    for (int k0 = 0; k0 < KSC; k0 += KT) {
        int k = k0 + lk4;
        int q = k >> 7;
        int d = k & 127;
        float4 hv = *(const float4*)(x2 + (size_t)hrow * DIMX + d);
        float4 pv = *(const float4*)(x2 + (size_t)prow * DIMX + d);
        float4 av;
        if (q == 0)      av = hv;
        else if (q == 1) av = pv;
        else if (q == 2) { av.x = hv.x * pv.x; av.y = hv.y * pv.y;
                           av.z = hv.z * pv.z; av.w = hv.w * pv.w; }
        else             { av.x = fabsf(hv.x - pv.x); av.y = fabsf(hv.y - pv.y);
                           av.z = fabsf(hv.z - pv.z); av.w = fabsf(hv.w - pv.w); }
        *(float4*)&As[lrow][lk4] = av;

        const float4* wsrc = (const float4*)(sw1 + (size_t)k0 * DIMX);
        ((float4*)Ws)[tid]       = wsrc[tid];
        ((float4*)Ws)[tid + 256] = wsrc[tid + 256];
        __syncthreads();

        #pragma unroll
        for (int kk = 0; kk < KT; kk += 4) {
            float4 wv0 = *(float4*)&Ws[kk + 0][oc];
            float4 wv1 = *(float4*)&Ws[kk + 1][oc];
            float4 wv2 = *(float4*)&Ws[kk + 2][oc];
            float4 wv3 = *(float4*)&Ws[kk + 3][oc];
            #pragma unroll
            for (int i = 0; i < 8; ++i) {
                float4 a4 = *(float4*)&As[nb + i][kk];
                acc[i][0] += a4.x * wv0.x + a4.y * wv1.x + a4.z * wv2.x + a4.w * wv3.x;
                acc[i][1] += a4.x * wv0.y + a4.y * wv1.y + a4.z * wv2.y + a4.w * wv3.y;
                acc[i][2] += a4.x * wv0.z + a4.y * wv1.z + a4.z * wv2.z + a4.w * wv3.z;
                acc[i][3] += a4.x * wv0.w + a4.y * wv1.w + a4.z * wv2.w + a4.w * wv3.w;
            }
        }
        __syncthreads();
    }

    float4 bv = *(const float4*)(sb1 + oc);
    #pragma unroll
    for (int i = 0; i < 8; ++i) {
        int n = n0 + nb + i;
        if (n < P) {
            float4 r;
            r.x = fmaxf(acc[i][0] + bv.x, 0.f);
            r.y = fmaxf(acc[i][1] + bv.y, 0.f);
            r.z = fmaxf(acc[i][2] + bv.z, 0.f);
            r.w = fmaxf(acc[i][3] + bv.w, 0.f);
            *(float4*)(hid + (size_t)n * DIMX + oc) = r;
        }
    }
}

// ---------------- scorer final dot: out = hid @ sw2 + sb2 ----------------

__global__ void k_scorer_out(const float* __restrict__ hid, const float* __restrict__ sw2,
                             const float* __restrict__ sb2, float* __restrict__ out, int P) {
    int tid = blockIdx.x * blockDim.x + threadIdx.x;
    int wave = tid >> 6;
    int lane = tid & 63;
    int half = lane >> 5, l32 = lane & 31;
    int pair = wave * 2 + half;
    if (pair >= P) return;
    float4 hv = *(const float4*)(hid + (size_t)pair * DIMX + l32 * 4);
    float4 wv = *(const float4*)(sw2 + l32 * 4);
    float s = hv.x * wv.x + hv.y * wv.y + hv.z * wv.z + hv.w * wv.w;
    #pragma unroll
    for (int off = 16; off; off >>= 1) s += __shfl_xor(s, off, 64);
    if (l32 == 0) out[pair] = s + sb2[0];
}

// ---------------- launcher ----------------

extern "C" void kernel_launch(void* const* d_in, const int* in_sizes, int n_in,
                              void* d_out, int out_size, void* d_ws, size_t ws_size,
                              hipStream_t stream) {
    const int*   ei       = (const int*)d_in[0];
    const int*   et       = (const int*)d_in[1];
    const int*   h_idx    = (const int*)d_in[2];
    const int*   p_idx    = (const int*)d_in[3];
    const float* node_emb = (const float*)d_in[4];
    const float* basis1   = (const float*)d_in[5];
    const float* comp1    = (const float*)d_in[6];
    const float* root1    = (const float*)d_in[7];
    const float* bias1    = (const float*)d_in[8];
    const float* basis2   = (const float*)d_in[9];
    const float* comp2    = (const float*)d_in[10];
    const float* root2    = (const float*)d_in[11];
    const float* bias2    = (const float*)d_in[12];
    const float* sw1      = (const float*)d_in[13];
    const float* sb1      = (const float*)d_in[14];
    const float* sw2      = (const float*)d_in[15];
    const float* sb2      = (const float*)d_in[16];
    float* out = (float*)d_out;

    int E  = in_sizes[1];
    int P  = in_sizes[2];
    int NN = in_sizes[4] / DIMX;   // 60000

    // workspace layout (floats; all region sizes are multiples of 4 floats)
    float* y      = (float*)d_ws;                                 // NN*768 (184 MB)
    float* hid    = y;                                            // alias (scorer phase)
    int*   cnt    = (int*)(y + (size_t)NN * YW);                  // NN*6
    float* invc   = (float*)(cnt + (size_t)NN * N_REL);           // NN*6
    float* out1   = invc + (size_t)NN * N_REL;                    // NN*128
    float* out2   = out1 + (size_t)NN * DIMX;                     // NN*128
    unsigned short* W2 = (unsigned short*)(out2 + (size_t)NN * DIMX); // 896*256 ushort
    int*   deg    = (int*)(W2 + (size_t)NWIDE * 256);             // NN
    int*   rowptr = deg + NN;                                     // NN+1
    int*   fillc  = rowptr + NN + 1;                              // NN
    int*   bsums  = fillc + NN;                                   // 64
    int*   pedge  = bsums + 64;                                   // E

    // A2 buffers alias dead fp32 regions:
    unsigned short* A2_l1 = (unsigned short*)out2;  // layer-1 A; dead before out2 written
    unsigned short* A2_l2 = (unsigned short*)out1;  // layer-2 A; in-place over out1

    int nScanB = (NN + 1023) / 1024;

    hipMemsetAsync(cnt, 0, (size_t)NN * N_REL * sizeof(int), stream);
    hipMemsetAsync(fillc, 0, (size_t)NN * sizeof(int), stream);

    // CSR build (shared by both layers)
    k_count<<<(E + 255) / 256, 256, 0, stream>>>(ei, et, E, cnt);
    k_invcnt<<<(NN * N_REL + 255) / 256, 256, 0, stream>>>(cnt, invc, NN * N_REL);
    k_deg<<<(NN + 255) / 256, 256, 0, stream>>>(cnt, deg, NN);
    k_scan1<<<nScanB, 256, 0, stream>>>(deg, bsums, NN);
    k_scan2<<<1, 64, 0, stream>>>(bsums, nScanB, rowptr, NN);
    k_scan3<<<nScanB, 256, 0, stream>>>(deg, bsums, rowptr, NN);
    k_fill<<<(E + 255) / 256, 256, 0, stream>>>(ei, et, E, rowptr, fillc, pedge);

    dim3 gemmGrid((NN + 63) / 64, N_REL + 1);
    dim3 wGrid(DIMX, N_REL + 1);
    int prepBlocks = (NN + 15) / 16;
    int gatherBlocks = ((size_t)NN * 64 + 255) / 256;

    // layer 1: y = emb @ [W1..W6]; out1 = emb @ root1 + bias1; gather adds means
    k_buildW2<<<wGrid, DIMX, 0, stream>>>(basis1, comp1, root1, W2);
    k_prepA<<<prepBlocks, 256, 0, stream>>>(node_emb, A2_l1, NN, 0);
    k_gemm_mfma<<<gemmGrid, 256, 0, stream>>>(A2_l1, W2, bias1, y, out1, NN);
    k_gather<<<gatherBlocks, 256, 0, stream>>>(pedge, rowptr, invc, y, out1, NN);

    // layer 2: A = relu(out1), packed in place over out1
    k_buildW2<<<wGrid, DIMX, 0, stream>>>(basis2, comp2, root2, W2);
    k_prepA<<<prepBlocks, 256, 0, stream>>>(out1, A2_l2, NN, 1);
    k_gemm_mfma<<<gemmGrid, 256, 0, stream>>>(A2_l2, W2, bias2, y, out2, NN);
    k_gather<<<gatherBlocks, 256, 0, stream>>>(pedge, rowptr, invc, y, out2, NN);

    // scorer (x2 = out2)
    k_scorer_gemm<<<(P + BN - 1) / BN, 256, 0, stream>>>(out2, h_idx, p_idx, sw1, sb1, hid, P);
    k_scorer_out<<<((size_t)P * 32 + 255) / 256, 256, 0, stream>>>(hid, sw2, sb2, out, P);
}

// Round 8
// 736.728 us; speedup vs baseline: 4.3349x; 1.2268x over previous
//
#include <hip/hip_runtime.h>
#include <hip/hip_bf16.h>
#include <cstdint>

#define DIMX   128
#define N_REL  6
#define N_BASES 30
#define N_HERB 5000
#define NWIDE  896   // 6 rel blocks + root block
#define YW     768   // y row width (rel blocks only)
#define KSC    512   // scorer feat dim
#define BN     64
#define KT     16

typedef __attribute__((ext_vector_type(8))) short short8v;
typedef __attribute__((ext_vector_type(4))) float f32x4;

__device__ __forceinline__ unsigned short f2bf_rne(float f) {
    union { float f; unsigned u; } v; v.f = f;
    unsigned u = v.u;
    u += 0x7fffu + ((u >> 16) & 1u);
    return (unsigned short)(u >> 16);
}
__device__ __forceinline__ float bf2f(unsigned short h) {
    union { unsigned u; float f; } v; v.u = ((unsigned)h) << 16;
    return v.f;
}

// ---------------- counting / prep ----------------

__global__ void k_count(const int* __restrict__ ei, const int* __restrict__ et,
                        int E, int* __restrict__ cnt) {
    int e = blockIdx.x * blockDim.x + threadIdx.x;
    if (e >= E) return;
    int dst = ei[E + e];
    int t   = et[e];
    atomicAdd(&cnt[dst * N_REL + t], 1);
}

__global__ void k_invcnt(const int* __restrict__ cnt, float* __restrict__ inv, int n) {
    int i = blockIdx.x * blockDim.x + threadIdx.x;
    if (i >= n) return;
    int c = cnt[i];
    inv[i] = 1.0f / (float)(c > 0 ? c : 1);
}

__global__ void k_deg(const int* __restrict__ cnt, int* __restrict__ deg, int n) {
    int i = blockIdx.x * blockDim.x + threadIdx.x;
    if (i >= n) return;
    int s = 0;
    #pragma unroll
    for (int t = 0; t < N_REL; ++t) s += cnt[i * N_REL + t];
    deg[i] = s;
}

// ---------------- exclusive scan over deg[n] -> rowptr ----------------

__global__ void k_scan1(const int* __restrict__ deg, int* __restrict__ bsums, int n) {
    __shared__ int ssum[256];
    int tid = threadIdx.x;
    int base = blockIdx.x * 1024;
    int local = 0;
    #pragma unroll
    for (int i = 0; i < 4; ++i) {
        int idx = base + tid * 4 + i;
        local += (idx < n) ? deg[idx] : 0;
    }
    ssum[tid] = local; __syncthreads();
    for (int off = 128; off; off >>= 1) {
        if (tid < off) ssum[tid] += ssum[tid + off];
        __syncthreads();
    }
    if (tid == 0) bsums[blockIdx.x] = ssum[0];
}

__global__ void k_scan2(int* __restrict__ bsums, int nb, int* __restrict__ rowptr, int n) {
    if (threadIdx.x == 0 && blockIdx.x == 0) {
        int run = 0;
        for (int b = 0; b < nb; ++b) { int t = bsums[b]; bsums[b] = run; run += t; }
        rowptr[n] = run;
    }
}

__global__ void k_scan3(const int* __restrict__ deg, const int* __restrict__ bsums,
                        int* __restrict__ rowptr, int n) {
    __shared__ int ssum[256];
    int tid = threadIdx.x;
    int base = blockIdx.x * 1024;
    int idx0 = base + tid * 4;
    int v[4]; int local = 0;
    #pragma unroll
    for (int i = 0; i < 4; ++i) {
        int idx = idx0 + i;
        v[i] = (idx < n) ? deg[idx] : 0;
        local += v[i];
    }
    ssum[tid] = local; __syncthreads();
    for (int off = 1; off < 256; off <<= 1) {
        int t = (tid >= off) ? ssum[tid - off] : 0;
        __syncthreads();
        ssum[tid] += t;
        __syncthreads();
    }
    int excl = ssum[tid] - local + bsums[blockIdx.x];
    #pragma unroll
    for (int i = 0; i < 4; ++i) {
        int idx = idx0 + i;
        if (idx < n) { rowptr[idx] = excl; excl += v[i]; }
    }
}

__global__ void k_fill(const int* __restrict__ ei, const int* __restrict__ et, int E,
                       const int* __restrict__ rowptr, int* __restrict__ fillc,
                       int* __restrict__ pedge) {
    int e = blockIdx.x * blockDim.x + threadIdx.x;
    if (e >= E) return;
    int src = ei[e];
    int dst = ei[E + e];
    int t   = et[e];
    int pos = atomicAdd(&fillc[dst], 1);
    pedge[rowptr[dst] + pos] = (src << 3) | t;
}

// ---------------- W2: packed transposed bf16 hi/lo weights ----------------
// W2[og][0..127]=hi(W[k][og]), W2[og][128..255]=lo, og = r*128+o (r=6 -> root).

__global__ void k_buildW2(const float* __restrict__ basis, const float* __restrict__ comp,
                          const float* __restrict__ root, unsigned short* __restrict__ W2) {
    int d = blockIdx.x;          // k index 0..127
    int r = blockIdx.y;          // 0..6
    int o = threadIdx.x;         // 0..127
    float v;
    if (r < N_REL) {
        float acc = 0.f;
        #pragma unroll
        for (int b = 0; b < N_BASES; ++b)
            acc += comp[r * N_BASES + b] * basis[((size_t)b * DIMX + d) * DIMX + o];
        v = acc;
    } else {
        v = root[(size_t)d * DIMX + o];
    }
    unsigned short hi = f2bf_rne(v);
    unsigned short lo = f2bf_rne(v - bf2f(hi));
    size_t og = (size_t)(r * DIMX + o);
    W2[og * 256 + d] = hi;
    W2[og * 256 + 128 + d] = lo;
}

// ---------------- A2 prep: fp32 rows -> packed bf16 {hi[128],lo[128]} ----------------

__global__ __launch_bounds__(256)
void k_prepA(const float* __restrict__ x, unsigned short* __restrict__ A2,
             int NN, int relu) {
    int row = blockIdx.x * 16 + (threadIdx.x >> 4);
    int c8  = (threadIdx.x & 15) * 8;
    float v[8];
    bool ok = (row < NN);
    if (ok) {
        float4 a = *(const float4*)(x + (size_t)row * DIMX + c8);
        float4 b = *(const float4*)(x + (size_t)row * DIMX + c8 + 4);
        v[0]=a.x; v[1]=a.y; v[2]=a.z; v[3]=a.w;
        v[4]=b.x; v[5]=b.y; v[6]=b.z; v[7]=b.w;
        if (relu) {
            #pragma unroll
            for (int i = 0; i < 8; ++i) v[i] = fmaxf(v[i], 0.f);
        }
    }
    __syncthreads();
    if (ok) {
        unsigned short hi[8], lo[8];
        #pragma unroll
        for (int i = 0; i < 8; ++i) {
            hi[i] = f2bf_rne(v[i]);
            lo[i] = f2bf_rne(v[i] - bf2f(hi[i]));
        }
        unsigned short* base = A2 + (size_t)row * 256;
        *(ulonglong2*)(base + c8)       = *(ulonglong2*)hi;
        *(ulonglong2*)(base + 128 + c8) = *(ulonglong2*)lo;
    }
}

// ---------------- MFMA node GEMM: [M,128] @ [128,896], bf16 hi/lo x3 ----------------
// grid (ceil(M/64), 7); 256 thr = 4 waves. Block: 64 rows x rel-block cb.
// Wave w owns out-subtile [w*32, w*32+32): B fragments resident in registers
// (16 short8v), loop over 4 independent 16-row M-tiles (8 A-loads + 24 MFMA each).
// cb<6: write y; cb==6: outbuf = . + bias (root path).

__global__ __launch_bounds__(256)
void k_gemm_mfma(const unsigned short* __restrict__ A2, const unsigned short* __restrict__ W2,
                 const float* __restrict__ bias, float* __restrict__ y,
                 float* __restrict__ outbuf, int NN) {
    int tid = threadIdx.x;
    int w  = tid >> 6;           // wave = out-subtile jj
    int l  = tid & 63;
    int cl = l & 15;
    int kg = (l >> 4) * 8;
    int cb = blockIdx.y;
    int rowBase = blockIdx.x * 64;
    if (rowBase >= NN) return;
    int nt = (NN - rowBase) >> 4; if (nt > 4) nt = 4;   // 16-row tiles (NN%16==0)

    int ocol0 = w * 32;
    const unsigned short* bB0 = W2 + (size_t)(cb * DIMX + ocol0 + cl) * 256 + kg;
    const unsigned short* bB1 = bB0 + 16 * 256;

    short8v b0h[4], b0l[4], b1h[4], b1l[4];
    #pragma unroll
    for (int k0 = 0; k0 < 4; ++k0) {
        b0h[k0] = *(const short8v*)(bB0 + k0 * 32);
        b0l[k0] = *(const short8v*)(bB0 + 128 + k0 * 32);
        b1h[k0] = *(const short8v*)(bB1 + k0 * 32);
        b1l[k0] = *(const short8v*)(bB1 + 128 + k0 * 32);
    }

    int rq = (l >> 4) * 4;   // C/D: col = l&15, row = (l>>4)*4 + reg

    for (int t = 0; t < nt; ++t) {
        int r0 = rowBase + t * 16;
        const unsigned short* aB = A2 + (size_t)(r0 + cl) * 256 + kg;
        f32x4 acc0 = (f32x4){0.f, 0.f, 0.f, 0.f};
        f32x4 acc1 = (f32x4){0.f, 0.f, 0.f, 0.f};
        #pragma unroll
        for (int k0 = 0; k0 < 4; ++k0) {
            short8v ah = *(const short8v*)(aB + k0 * 32);
            short8v al = *(const short8v*)(aB + 128 + k0 * 32);
            acc0 = __builtin_amdgcn_mfma_f32_16x16x32_bf16(ah, b0h[k0], acc0, 0, 0, 0);
            acc0 = __builtin_amdgcn_mfma_f32_16x16x32_bf16(al, b0h[k0], acc0, 0, 0, 0);
            acc0 = __builtin_amdgcn_mfma_f32_16x16x32_bf16(ah, b0l[k0], acc0, 0, 0, 0);
            acc1 = __builtin_amdgcn_mfma_f32_16x16x32_bf16(ah, b1h[k0], acc1, 0, 0, 0);
            acc1 = __builtin_amdgcn_mfma_f32_16x16x32_bf16(al, b1h[k0], acc1, 0, 0, 0);
            acc1 = __builtin_amdgcn_mfma_f32_16x16x32_bf16(ah, b1l[k0], acc1, 0, 0, 0);
        }
        if (cb < N_REL) {
            float* yb = y + (size_t)(r0 + rq) * YW + cb * DIMX + ocol0 + cl;
            #pragma unroll
            for (int q = 0; q < 4; ++q) {
                yb[(size_t)q * YW]      = acc0[q];
                yb[(size_t)q * YW + 16] = acc1[q];
            }
        } else {
            float bv0 = bias[ocol0 + cl];
            float bv1 = bias[ocol0 + 16 + cl];
            float* ob = outbuf + (size_t)(r0 + rq) * DIMX + ocol0 + cl;
            #pragma unroll
            for (int q = 0; q < 4; ++q) {
                ob[(size_t)q * DIMX]      = acc0[q] + bv0;
                ob[(size_t)q * DIMX + 16] = acc1[q] + bv1;
            }
        }
    }
}

// ---------------- CSR gather: outbuf[dst] += sum_e y[src_e, t_e*128:] * invc[dst,t_e] ----

__global__ __launch_bounds__(256)
void k_gather(const int* __restrict__ pedge, const int* __restrict__ rowptr,
              const float* __restrict__ invc, const float* __restrict__ y,
              float* __restrict__ outbuf, int NN) {
    int wid = (blockIdx.x * blockDim.x + threadIdx.x) >> 6;
    if (wid >= NN) return;
    int lane = threadIdx.x & 63;
    int dst = wid;
    int j0 = rowptr[dst], j1 = rowptr[dst + 1];

    float* op = outbuf + (size_t)dst * DIMX + lane * 2;
    float2 acc = *(float2*)op;

    int j = j0;
    for (; j + 1 < j1; j += 2) {
        int pa = pedge[j], pb = pedge[j + 1];
        int ta = pa & 7, tb = pb & 7;
        int sa = pa >> 3, sb = pb >> 3;
        float fa = invc[dst * N_REL + ta];
        float fb = invc[dst * N_REL + tb];
        float2 va = *(const float2*)(y + (size_t)sa * YW + ta * DIMX + lane * 2);
        float2 vb = *(const float2*)(y + (size_t)sb * YW + tb * DIMX + lane * 2);
        acc.x += va.x * fa + vb.x * fb;
        acc.y += va.y * fa + vb.y * fb;
    }
    if (j < j1) {
        int pa = pedge[j];
        int ta = pa & 7;
        int sa = pa >> 3;
        float fa = invc[dst * N_REL + ta];
        float2 va = *(const float2*)(y + (size_t)sa * YW + ta * DIMX + lane * 2);
        acc.x += va.x * fa;
        acc.y += va.y * fa;
    }
    *(float2*)op = acc;
}

// ---------------- scorer GEMM: hid = relu(feat @ sw1 + sb1) ----------------

__global__ __launch_bounds__(256)
void k_scorer_gemm(const float* __restrict__ x2, const int* __restrict__ h_idx,
                   const int* __restrict__ p_idx, const float* __restrict__ sw1,
                   const float* __restrict__ sb1, float* __restrict__ hid, int P) {
    __shared__ float As[BN][KT];
    __shared__ float Ws[KT][DIMX];
    int tid = threadIdx.x;
    int n0 = blockIdx.x * BN;

    int lrow = tid >> 2;
    int lk4  = (tid & 3) * 4;
    int ng = n0 + lrow; if (ng >= P) ng = P - 1;
    int hrow = h_idx[ng];
    int prow = N_HERB + p_idx[ng];

    int oc = (tid & 31) * 4;
    int nb = (tid >> 5) * 8;

    float acc[8][4];
    #pragma unroll
    for (int i = 0; i < 8; ++i)
        #pragma unroll
        for (int j = 0; j < 4; ++j) acc[i][j] = 0.f;

    for (int k0 = 0; k0 < KSC; k0 += KT) {
        int k = k0 + lk4;
        int q = k >> 7;
        int d = k & 127;
        float4 hv = *(const float4*)(x2 + (size_t)hrow * DIMX + d);
        float4 pv = *(const float4*)(x2 + (size_t)prow * DIMX + d);
        float4 av;
        if (q == 0)      av = hv;
        else if (q == 1) av = pv;
        else if (q == 2) { av.x = hv.x * pv.x; av.y = hv.y * pv.y;
                           av.z = hv.z * pv.z; av.w = hv.w * pv.w; }
        else             { av.x = fabsf(hv.x - pv.x); av.y = fabsf(hv.y - pv.y);
                           av.z = fabsf(hv.z - pv.z); av.w = fabsf(hv.w - pv.w); }
        *(float4*)&As[lrow][lk4] = av;

        const float4* wsrc = (const float4*)(sw1 + (size_t)k0 * DIMX);
        ((float4*)Ws)[tid]       = wsrc[tid];
        ((float4*)Ws)[tid + 256] = wsrc[tid + 256];
        __syncthreads();

        #pragma unroll
        for (int kk = 0; kk < KT; kk += 4) {
            float4 wv0 = *(float4*)&Ws[kk + 0][oc];
            float4 wv1 = *(float4*)&Ws[kk + 1][oc];
            float4 wv2 = *(float4*)&Ws[kk + 2][oc];
            float4 wv3 = *(float4*)&Ws[kk + 3][oc];
            #pragma unroll
            for (int i = 0; i < 8; ++i) {
                float4 a4 = *(float4*)&As[nb + i][kk];
                acc[i][0] += a4.x * wv0.x + a4.y * wv1.x + a4.z * wv2.x + a4.w * wv3.x;
                acc[i][1] += a4.x * wv0.y + a4.y * wv1.y + a4.z * wv2.y + a4.w * wv3.y;
                acc[i][2] += a4.x * wv0.z + a4.y * wv1.z + a4.z * wv2.z + a4.w * wv3.z;
                acc[i][3] += a4.x * wv0.w + a4.y * wv1.w + a4.z * wv2.w + a4.w * wv3.w;
            }
        }
        __syncthreads();
    }

    float4 bv = *(const float4*)(sb1 + oc);
    #pragma unroll
    for (int i = 0; i < 8; ++i) {
        int n = n0 + nb + i;
        if (n < P) {
            float4 r;
            r.x = fmaxf(acc[i][0] + bv.x, 0.f);
            r.y = fmaxf(acc[i][1] + bv.y, 0.f);
            r.z = fmaxf(acc[i][2] + bv.z, 0.f);
            r.w = fmaxf(acc[i][3] + bv.w, 0.f);
            *(float4*)(hid + (size_t)n * DIMX + oc) = r;
        }
    }
}

// ---------------- scorer final dot: out = hid @ sw2 + sb2 ----------------

__global__ void k_scorer_out(const float* __restrict__ hid, const float* __restrict__ sw2,
                             const float* __restrict__ sb2, float* __restrict__ out, int P) {
    int tid = blockIdx.x * blockDim.x + threadIdx.x;
    int wave = tid >> 6;
    int lane = tid & 63;
    int half = lane >> 5, l32 = lane & 31;
    int pair = wave * 2 + half;
    if (pair >= P) return;
    float4 hv = *(const float4*)(hid + (size_t)pair * DIMX + l32 * 4);
    float4 wv = *(const float4*)(sw2 + l32 * 4);
    float s = hv.x * wv.x + hv.y * wv.y + hv.z * wv.z + hv.w * wv.w;
    #pragma unroll
    for (int off = 16; off; off >>= 1) s += __shfl_xor(s, off, 64);
    if (l32 == 0) out[pair] = s + sb2[0];
}

// ---------------- launcher ----------------

extern "C" void kernel_launch(void* const* d_in, const int* in_sizes, int n_in,
                              void* d_out, int out_size, void* d_ws, size_t ws_size,
                              hipStream_t stream) {
    const int*   ei       = (const int*)d_in[0];
    const int*   et       = (const int*)d_in[1];
    const int*   h_idx    = (const int*)d_in[2];
    const int*   p_idx    = (const int*)d_in[3];
    const float* node_emb = (const float*)d_in[4];
    const float* basis1   = (const float*)d_in[5];
    const float* comp1    = (const float*)d_in[6];
    const float* root1    = (const float*)d_in[7];
    const float* bias1    = (const float*)d_in[8];
    const float* basis2   = (const float*)d_in[9];
    const float* comp2    = (const float*)d_in[10];
    const float* root2    = (const float*)d_in[11];
    const float* bias2    = (const float*)d_in[12];
    const float* sw1      = (const float*)d_in[13];
    const float* sb1      = (const float*)d_in[14];
    const float* sw2      = (const float*)d_in[15];
    const float* sb2      = (const float*)d_in[16];
    float* out = (float*)d_out;

    int E  = in_sizes[1];
    int P  = in_sizes[2];
    int NN = in_sizes[4] / DIMX;   // 60000

    // workspace layout (floats; all region sizes are multiples of 4 floats)
    float* y      = (float*)d_ws;                                 // NN*768 (184 MB)
    float* hid    = y;                                            // alias (scorer phase)
    int*   cnt    = (int*)(y + (size_t)NN * YW);                  // NN*6
    float* invc   = (float*)(cnt + (size_t)NN * N_REL);           // NN*6
    float* out1   = invc + (size_t)NN * N_REL;                    // NN*128
    float* out2   = out1 + (size_t)NN * DIMX;                     // NN*128
    unsigned short* W2 = (unsigned short*)(out2 + (size_t)NN * DIMX); // 896*256 ushort
    int*   deg    = (int*)(W2 + (size_t)NWIDE * 256);             // NN
    int*   rowptr = deg + NN;                                     // NN+1
    int*   fillc  = rowptr + NN + 1;                              // NN
    int*   bsums  = fillc + NN;                                   // 64
    int*   pedge  = bsums + 64;                                   // E

    // A2 buffers alias dead fp32 regions:
    unsigned short* A2_l1 = (unsigned short*)out2;  // layer-1 A; dead before out2 written
    unsigned short* A2_l2 = (unsigned short*)out1;  // layer-2 A; in-place over out1

    int nScanB = (NN + 1023) / 1024;

    hipMemsetAsync(cnt, 0, (size_t)NN * N_REL * sizeof(int), stream);
    hipMemsetAsync(fillc, 0, (size_t)NN * sizeof(int), stream);

    // CSR build (shared by both layers)
    k_count<<<(E + 255) / 256, 256, 0, stream>>>(ei, et, E, cnt);
    k_invcnt<<<(NN * N_REL + 255) / 256, 256, 0, stream>>>(cnt, invc, NN * N_REL);
    k_deg<<<(NN + 255) / 256, 256, 0, stream>>>(cnt, deg, NN);
    k_scan1<<<nScanB, 256, 0, stream>>>(deg, bsums, NN);
    k_scan2<<<1, 64, 0, stream>>>(bsums, nScanB, rowptr, NN);
    k_scan3<<<nScanB, 256, 0, stream>>>(deg, bsums, rowptr, NN);
    k_fill<<<(E + 255) / 256, 256, 0, stream>>>(ei, et, E, rowptr, fillc, pedge);

    dim3 gemmGrid((NN + 63) / 64, N_REL + 1);
    dim3 wGrid(DIMX, N_REL + 1);
    int prepBlocks = (NN + 15) / 16;
    int gatherBlocks = ((size_t)NN * 64 + 255) / 256;

    // layer 1: y = emb @ [W1..W6]; out1 = emb @ root1 + bias1; gather adds means
    k_buildW2<<<wGrid, DIMX, 0, stream>>>(basis1, comp1, root1, W2);
    k_prepA<<<prepBlocks, 256, 0, stream>>>(node_emb, A2_l1, NN, 0);
    k_gemm_mfma<<<gemmGrid, 256, 0, stream>>>(A2_l1, W2, bias1, y, out1, NN);
    k_gather<<<gatherBlocks, 256, 0, stream>>>(pedge, rowptr, invc, y, out1, NN);

    // layer 2: A = relu(out1), packed in place over out1
    k_buildW2<<<wGrid, DIMX, 0, stream>>>(basis2, comp2, root2, W2);
    k_prepA<<<prepBlocks, 256, 0, stream>>>(out1, A2_l2, NN, 1);
    k_gemm_mfma<<<gemmGrid, 256, 0, stream>>>(A2_l2, W2, bias2, y, out2, NN);
    k_gather<<<gatherBlocks, 256, 0, stream>>>(pedge, rowptr, invc, y, out2, NN);

    // scorer (x2 = out2)
    k_scorer_gemm<<<(P + BN - 1) / BN, 256, 0, stream>>>(out2, h_idx, p_idx, sw1, sb1, hid, P);
    k_scorer_out<<<((size_t)P * 32 + 255) / 256, 256, 0, stream>>>(hid, sw2, sb2, out, P);
}

// Round 10
// 733.671 us; speedup vs baseline: 4.3529x; 1.0042x over previous
//
#include <hip/hip_runtime.h>
#include <hip/hip_bf16.h>
#include <cstdint>

#define DIMX   128
#define N_REL  6
#define N_BASES 30
#define N_HERB 5000
#define NWIDE  896   // 6 rel blocks + root block
#define YW     768   // y row width (rel blocks only), in bf16 elements
#define KSC    512   // scorer feat dim
#define BN     64
#define KT     16

typedef __attribute__((ext_vector_type(8))) short short8v;
typedef __attribute__((ext_vector_type(4))) float f32x4;

__device__ __forceinline__ unsigned short f2bf_rne(float f) {
    union { float f; unsigned u; } v; v.f = f;
    unsigned u = v.u;
    u += 0x7fffu + ((u >> 16) & 1u);
    return (unsigned short)(u >> 16);
}
__device__ __forceinline__ float bf2f(unsigned short h) {
    union { unsigned u; float f; } v; v.u = ((unsigned)h) << 16;
    return v.f;
}

// ---------------- counting / prep ----------------

__global__ void k_count(const int* __restrict__ ei, const int* __restrict__ et,
                        int E, int* __restrict__ cnt) {
    int e = blockIdx.x * blockDim.x + threadIdx.x;
    if (e >= E) return;
    int dst = ei[E + e];
    int t   = et[e];
    atomicAdd(&cnt[dst * N_REL + t], 1);
}

__global__ void k_invcnt(const int* __restrict__ cnt, float* __restrict__ inv, int n) {
    int i = blockIdx.x * blockDim.x + threadIdx.x;
    if (i >= n) return;
    int c = cnt[i];
    inv[i] = 1.0f / (float)(c > 0 ? c : 1);
}

__global__ void k_deg(const int* __restrict__ cnt, int* __restrict__ deg, int n) {
    int i = blockIdx.x * blockDim.x + threadIdx.x;
    if (i >= n) return;
    int s = 0;
    #pragma unroll
    for (int t = 0; t < N_REL; ++t) s += cnt[i * N_REL + t];
    deg[i] = s;
}

// ---------------- exclusive scan over deg[n] -> rowptr ----------------

__global__ void k_scan1(const int* __restrict__ deg, int* __restrict__ bsums, int n) {
    __shared__ int ssum[256];
    int tid = threadIdx.x;
    int base = blockIdx.x * 1024;
    int local = 0;
    #pragma unroll
    for (int i = 0; i < 4; ++i) {
        int idx = base + tid * 4 + i;
        local += (idx < n) ? deg[idx] : 0;
    }
    ssum[tid] = local; __syncthreads();
    for (int off = 128; off; off >>= 1) {
        if (tid < off) ssum[tid] += ssum[tid + off];
        __syncthreads();
    }
    if (tid == 0) bsums[blockIdx.x] = ssum[0];
}

__global__ void k_scan2(int* __restrict__ bsums, int nb, int* __restrict__ rowptr, int n) {
    if (threadIdx.x == 0 && blockIdx.x == 0) {
        int run = 0;
        for (int b = 0; b < nb; ++b) { int t = bsums[b]; bsums[b] = run; run += t; }
        rowptr[n] = run;
    }
}

__global__ void k_scan3(const int* __restrict__ deg, const int* __restrict__ bsums,
                        int* __restrict__ rowptr, int n) {
    __shared__ int ssum[256];
    int tid = threadIdx.x;
    int base = blockIdx.x * 1024;
    int idx0 = base + tid * 4;
    int v[4]; int local = 0;
    #pragma unroll
    for (int i = 0; i < 4; ++i) {
        int idx = idx0 + i;
        v[i] = (idx < n) ? deg[idx] : 0;
        local += v[i];
    }
    ssum[tid] = local; __syncthreads();
    for (int off = 1; off < 256; off <<= 1) {
        int t = (tid >= off) ? ssum[tid - off] : 0;
        __syncthreads();
        ssum[tid] += t;
        __syncthreads();
    }
    int excl = ssum[tid] - local + bsums[blockIdx.x];
    #pragma unroll
    for (int i = 0; i < 4; ++i) {
        int idx = idx0 + i;
        if (idx < n) { rowptr[idx] = excl; excl += v[i]; }
    }
}

__global__ void k_fill(const int* __restrict__ ei, const int* __restrict__ et, int E,
                       const int* __restrict__ rowptr, int* __restrict__ fillc,
                       int* __restrict__ pedge) {
    int e = blockIdx.x * blockDim.x + threadIdx.x;
    if (e >= E) return;
    int src = ei[e];
    int dst = ei[E + e];
    int t   = et[e];
    int pos = atomicAdd(&fillc[dst], 1);
    pedge[rowptr[dst] + pos] = (src << 3) | t;
}

// ---------------- W2: packed transposed bf16 hi/lo weights ----------------
// W2[og][0..127]=hi(W[k][og]), W2[og][128..255]=lo, og = r*128+o (r=6 -> root).

__global__ void k_buildW2(const float* __restrict__ basis, const float* __restrict__ comp,
                          const float* __restrict__ root, unsigned short* __restrict__ W2) {
    int d = blockIdx.x;          // k index 0..127
    int r = blockIdx.y;          // 0..6
    int o = threadIdx.x;         // 0..127
    float v;
    if (r < N_REL) {
        float acc = 0.f;
        #pragma unroll
        for (int b = 0; b < N_BASES; ++b)
            acc += comp[r * N_BASES + b] * basis[((size_t)b * DIMX + d) * DIMX + o];
        v = acc;
    } else {
        v = root[(size_t)d * DIMX + o];
    }
    unsigned short hi = f2bf_rne(v);
    unsigned short lo = f2bf_rne(v - bf2f(hi));
    size_t og = (size_t)(r * DIMX + o);
    W2[og * 256 + d] = hi;
    W2[og * 256 + 128 + d] = lo;
}

// ---------------- A2 prep: fp32 rows -> packed bf16 {hi[128],lo[128]} ----------------

__global__ __launch_bounds__(256)
void k_prepA(const float* __restrict__ x, unsigned short* __restrict__ A2,
             int NN, int relu) {
    int row = blockIdx.x * 16 + (threadIdx.x >> 4);
    int c8  = (threadIdx.x & 15) * 8;
    float v[8];
    bool ok = (row < NN);
    if (ok) {
        float4 a = *(const float4*)(x + (size_t)row * DIMX + c8);
        float4 b = *(const float4*)(x + (size_t)row * DIMX + c8 + 4);
        v[0]=a.x; v[1]=a.y; v[2]=a.z; v[3]=a.w;
        v[4]=b.x; v[5]=b.y; v[6]=b.z; v[7]=b.w;
        if (relu) {
            #pragma unroll
            for (int i = 0; i < 8; ++i) v[i] = fmaxf(v[i], 0.f);
        }
    }
    __syncthreads();
    if (ok) {
        unsigned short hi[8], lo[8];
        #pragma unroll
        for (int i = 0; i < 8; ++i) {
            hi[i] = f2bf_rne(v[i]);
            lo[i] = f2bf_rne(v[i] - bf2f(hi[i]));
        }
        unsigned short* base = A2 + (size_t)row * 256;
        *(ulonglong2*)(base + c8)       = *(ulonglong2*)hi;
        *(ulonglong2*)(base + 128 + c8) = *(ulonglong2*)lo;
    }
}

// ---------------- MFMA node GEMM: [M,128] @ [128,896], bf16 hi/lo x3 ----------------
// grid (ceil(M/64)); 256 thr = 4 waves. Block: 64 rows; cb loop INSIDE the kernel
// so A-rows are re-read L1/L2-hot instead of from HBM. Wave w owns out-subtile
// [w*32, w*32+32) of each cb block; B fragments in registers per cb.
// cb<6: write y (bf16); cb==6: outbuf = . + bias (fp32 root path).

__global__ __launch_bounds__(256)
void k_gemm_mfma(const unsigned short* __restrict__ A2, const unsigned short* __restrict__ W2,
                 const float* __restrict__ bias, unsigned short* __restrict__ y,
                 float* __restrict__ outbuf, int NN) {
    int tid = threadIdx.x;
    int w  = tid >> 6;           // wave = out-subtile jj
    int l  = tid & 63;
    int cl = l & 15;
    int kg = (l >> 4) * 8;
    int rowBase = blockIdx.x * 64;
    if (rowBase >= NN) return;
    int nt = (NN - rowBase) >> 4; if (nt > 4) nt = 4;   // 16-row tiles (NN%16==0)

    int ocol0 = w * 32;
    int rq = (l >> 4) * 4;   // C/D: col = l&15, row = (l>>4)*4 + reg
    float bv0 = bias[ocol0 + cl];
    float bv1 = bias[ocol0 + 16 + cl];

    for (int cb = 0; cb < N_REL + 1; ++cb) {
        const unsigned short* bB0 = W2 + (size_t)(cb * DIMX + ocol0 + cl) * 256 + kg;
        const unsigned short* bB1 = bB0 + 16 * 256;

        short8v b0h[4], b0l[4], b1h[4], b1l[4];
        #pragma unroll
        for (int k0 = 0; k0 < 4; ++k0) {
            b0h[k0] = *(const short8v*)(bB0 + k0 * 32);
            b0l[k0] = *(const short8v*)(bB0 + 128 + k0 * 32);
            b1h[k0] = *(const short8v*)(bB1 + k0 * 32);
            b1l[k0] = *(const short8v*)(bB1 + 128 + k0 * 32);
        }

        for (int t = 0; t < nt; ++t) {
            int r0 = rowBase + t * 16;
            const unsigned short* aB = A2 + (size_t)(r0 + cl) * 256 + kg;
            f32x4 acc0 = (f32x4){0.f, 0.f, 0.f, 0.f};
            f32x4 acc1 = (f32x4){0.f, 0.f, 0.f, 0.f};
            #pragma unroll
            for (int k0 = 0; k0 < 4; ++k0) {
                short8v ah = *(const short8v*)(aB + k0 * 32);
                short8v al = *(const short8v*)(aB + 128 + k0 * 32);
                acc0 = __builtin_amdgcn_mfma_f32_16x16x32_bf16(ah, b0h[k0], acc0, 0, 0, 0);
                acc0 = __builtin_amdgcn_mfma_f32_16x16x32_bf16(al, b0h[k0], acc0, 0, 0, 0);
                acc0 = __builtin_amdgcn_mfma_f32_16x16x32_bf16(ah, b0l[k0], acc0, 0, 0, 0);
                acc1 = __builtin_amdgcn_mfma_f32_16x16x32_bf16(ah, b1h[k0], acc1, 0, 0, 0);
                acc1 = __builtin_amdgcn_mfma_f32_16x16x32_bf16(al, b1h[k0], acc1, 0, 0, 0);
                acc1 = __builtin_amdgcn_mfma_f32_16x16x32_bf16(ah, b1l[k0], acc1, 0, 0, 0);
            }
            if (cb < N_REL) {
                unsigned short* yb = y + (size_t)(r0 + rq) * YW + cb * DIMX + ocol0 + cl;
                #pragma unroll
                for (int q = 0; q < 4; ++q) {
                    yb[(size_t)q * YW]      = f2bf_rne(acc0[q]);
                    yb[(size_t)q * YW + 16] = f2bf_rne(acc1[q]);
                }
            } else {
                float* ob = outbuf + (size_t)(r0 + rq) * DIMX + ocol0 + cl;
                #pragma unroll
                for (int q = 0; q < 4; ++q) {
                    ob[(size_t)q * DIMX]      = acc0[q] + bv0;
                    ob[(size_t)q * DIMX + 16] = acc1[q] + bv1;
                }
            }
        }
    }
}

// ---------------- CSR gather: outbuf[dst] += sum_e bf16(y[src_e, t_e*128:]) * invc[dst,t_e] ----
// One wave per dst; lane handles 2 cols via one dword load per edge. No atomics.

__global__ __launch_bounds__(256)
void k_gather(const int* __restrict__ pedge, const int* __restrict__ rowptr,
              const float* __restrict__ invc, const unsigned short* __restrict__ y,
              float* __restrict__ outbuf, int NN) {
    int wid = (blockIdx.x * blockDim.x + threadIdx.x) >> 6;
    if (wid >= NN) return;
    int lane = threadIdx.x & 63;
    int dst = wid;
    int j0 = rowptr[dst], j1 = rowptr[dst + 1];

    float* op = outbuf + (size_t)dst * DIMX + lane * 2;
    float2 acc = *(float2*)op;

    int j = j0;
    for (; j + 1 < j1; j += 2) {
        int pa = pedge[j], pb = pedge[j + 1];
        int ta = pa & 7, tb = pb & 7;
        int sa = pa >> 3, sb = pb >> 3;
        float fa = invc[dst * N_REL + ta];
        float fb = invc[dst * N_REL + tb];
        unsigned va = *(const unsigned*)(y + (size_t)sa * YW + ta * DIMX + lane * 2);
        unsigned vb = *(const unsigned*)(y + (size_t)sb * YW + tb * DIMX + lane * 2);
        acc.x += bf2f((unsigned short)(va & 0xffff)) * fa
               + bf2f((unsigned short)(vb & 0xffff)) * fb;
        acc.y += bf2f((unsigned short)(va >> 16)) * fa
               + bf2f((unsigned short)(vb >> 16)) * fb;
    }
    if (j < j1) {
        int pa = pedge[j];
        int ta = pa & 7;
        int sa = pa >> 3;
        float fa = invc[dst * N_REL + ta];
        unsigned va = *(const unsigned*)(y + (size_t)sa * YW + ta * DIMX + lane * 2);
        acc.x += bf2f((unsigned short)(va & 0xffff)) * fa;
        acc.y += bf2f((unsigned short)(va >> 16)) * fa;
    }
    *(float2*)op = acc;
}

// ---------------- scorer GEMM: hid = relu(feat @ sw1 + sb1) ----------------

__global__ __launch_bounds__(256)
void k_scorer_gemm(const float* __restrict__ x2, const int* __restrict__ h_idx,
                   const int* __restrict__ p_idx, const float* __restrict__ sw1,
                   const float* __restrict__ sb1, float* __restrict__ hid, int P) {
    __shared__ float As[BN][KT];
    __shared__ float Ws[KT][DIMX];
    int tid = threadIdx.x;
    int n0 = blockIdx.x * BN;

    int lrow = tid >> 2;
    int lk4  = (tid & 3) * 4;
    int ng = n0 + lrow; if (ng >= P) ng = P - 1;
    int hrow = h_idx[ng];
    int prow = N_HERB + p_idx[ng];

    int oc = (tid & 31) * 4;
    int nb = (tid >> 5) * 8;

    float acc[8][4];
    #pragma unroll
    for (int i = 0; i < 8; ++i)
        #pragma unroll
        for (int j = 0; j < 4; ++j) acc[i][j] = 0.f;

    for (int k0 = 0; k0 < KSC; k0 += KT) {
        int k = k0 + lk4;
        int q = k >> 7;
        int d = k & 127;
        float4 hv = *(const float4*)(x2 + (size_t)hrow * DIMX + d);
        float4 pv = *(const float4*)(x2 + (size_t)prow * DIMX + d);
        float4 av;
        if (q == 0)      av = hv;
        else if (q == 1) av = pv;
        else if (q == 2) { av.x = hv.x * pv.x; av.y = hv.y * pv.y;
                           av.z = hv.z * pv.z; av.w = hv.w * pv.w; }
        else             { av.x = fabsf(hv.x - pv.x); av.y = fabsf(hv.y - pv.y);
                           av.z = fabsf(hv.z - pv.z); av.w = fabsf(hv.w - pv.w); }
        *(float4*)&As[lrow][lk4] = av;

        const float4* wsrc = (const float4*)(sw1 + (size_t)k0 * DIMX);
        ((float4*)Ws)[tid]       = wsrc[tid];
        ((float4*)Ws)[tid + 256] = wsrc[tid + 256];
        __syncthreads();

        #pragma unroll
        for (int kk = 0; kk < KT; kk += 4) {
            float4 wv0 = *(float4*)&Ws[kk + 0][oc];
            float4 wv1 = *(float4*)&Ws[kk + 1][oc];
            float4 wv2 = *(float4*)&Ws[kk + 2][oc];
            float4 wv3 = *(float4*)&Ws[kk + 3][oc];
            #pragma unroll
            for (int i = 0; i < 8; ++i) {
                float4 a4 = *(float4*)&As[nb + i][kk];
                acc[i][0] += a4.x * wv0.x + a4.y * wv1.x + a4.z * wv2.x + a4.w * wv3.x;
                acc[i][1] += a4.x * wv0.y + a4.y * wv1.y + a4.z * wv2.y + a4.w * wv3.y;
                acc[i][2] += a4.x * wv0.z + a4.y * wv1.z + a4.z * wv2.z + a4.w * wv3.z;
                acc[i][3] += a4.x * wv0.w + a4.y * wv1.w + a4.z * wv2.w + a4.w * wv3.w;
            }
        }
        __syncthreads();
    }

    float4 bv = *(const float4*)(sb1 + oc);
    #pragma unroll
    for (int i = 0; i < 8; ++i) {
        int n = n0 + nb + i;
        if (n < P) {
            float4 r;
            r.x = fmaxf(acc[i][0] + bv.x, 0.f);
            r.y = fmaxf(acc[i][1] + bv.y, 0.f);
            r.z = fmaxf(acc[i][2] + bv.z, 0.f);
            r.w = fmaxf(acc[i][3] + bv.w, 0.f);
            *(float4*)(hid + (size_t)n * DIMX + oc) = r;
        }
    }
}

// ---------------- scorer final dot: out = hid @ sw2 + sb2 ----------------

__global__ void k_scorer_out(const float* __restrict__ hid, const float* __restrict__ sw2,
                             const float* __restrict__ sb2, float* __restrict__ out, int P) {
    int tid = blockIdx.x * blockDim.x + threadIdx.x;
    int wave = tid >> 6;
    int lane = tid & 63;
    int half = lane >> 5, l32 = lane & 31;
    int pair = wave * 2 + half;
    if (pair >= P) return;
    float4 hv = *(const float4*)(hid + (size_t)pair * DIMX + l32 * 4);
    float4 wv = *(const float4*)(sw2 + l32 * 4);
    float s = hv.x * wv.x + hv.y * wv.y + hv.z * wv.z + hv.w * wv.w;
    #pragma unroll
    for (int off = 16; off; off >>= 1) s += __shfl_xor(s, off, 64);
    if (l32 == 0) out[pair] = s + sb2[0];
}

// ---------------- launcher ----------------

extern "C" void kernel_launch(void* const* d_in, const int* in_sizes, int n_in,
                              void* d_out, int out_size, void* d_ws, size_t ws_size,
                              hipStream_t stream) {
    const int*   ei       = (const int*)d_in[0];
    const int*   et       = (const int*)d_in[1];
    const int*   h_idx    = (const int*)d_in[2];
    const int*   p_idx    = (const int*)d_in[3];
    const float* node_emb = (const float*)d_in[4];
    const float* basis1   = (const float*)d_in[5];
    const float* comp1    = (const float*)d_in[6];
    const float* root1    = (const float*)d_in[7];
    const float* bias1    = (const float*)d_in[8];
    const float* basis2   = (const float*)d_in[9];
    const float* comp2    = (const float*)d_in[10];
    const float* root2    = (const float*)d_in[11];
    const float* bias2    = (const float*)d_in[12];
    const float* sw1      = (const float*)d_in[13];
    const float* sb1      = (const float*)d_in[14];
    const float* sw2      = (const float*)d_in[15];
    const float* sb2      = (const float*)d_in[16];
    float* out = (float*)d_out;

    int E  = in_sizes[1];
    int P  = in_sizes[2];
    int NN = in_sizes[4] / DIMX;   // 60000

    // workspace layout
    unsigned short* y = (unsigned short*)d_ws;                    // NN*768 bf16 (92 MB)
    float* hid    = (float*)d_ws;                                 // alias (scorer phase only)
    float* fbase  = (float*)(y + (size_t)NN * YW);                // after y region
    int*   cnt    = (int*)fbase;                                  // NN*6
    float* invc   = (float*)(cnt + (size_t)NN * N_REL);           // NN*6
    float* out1   = invc + (size_t)NN * N_REL;                    // NN*128
    float* out2   = out1 + (size_t)NN * DIMX;                     // NN*128
    unsigned short* W2 = (unsigned short*)(out2 + (size_t)NN * DIMX); // 896*256 ushort
    int*   deg    = (int*)(W2 + (size_t)NWIDE * 256);             // NN
    int*   rowptr = deg + NN;                                     // NN+1
    int*   fillc  = rowptr + NN + 1;                              // NN
    int*   bsums  = fillc + NN;                                   // 64
    int*   pedge  = bsums + 64;                                   // E

    // A2 buffers alias dead fp32 regions:
    unsigned short* A2_l1 = (unsigned short*)out2;  // layer-1 A; dead before out2 written
    unsigned short* A2_l2 = (unsigned short*)out1;  // layer-2 A; in-place over out1

    int nScanB = (NN + 1023) / 1024;

    hipMemsetAsync(cnt, 0, (size_t)NN * N_REL * sizeof(int), stream);
    hipMemsetAsync(fillc, 0, (size_t)NN * sizeof(int), stream);

    // CSR build (shared by both layers)
    k_count<<<(E + 255) / 256, 256, 0, stream>>>(ei, et, E, cnt);
    k_invcnt<<<(NN * N_REL + 255) / 256, 256, 0, stream>>>(cnt, invc, NN * N_REL);
    k_deg<<<(NN + 255) / 256, 256, 0, stream>>>(cnt, deg, NN);
    k_scan1<<<nScanB, 256, 0, stream>>>(deg, bsums, NN);
    k_scan2<<<1, 64, 0, stream>>>(bsums, nScanB, rowptr, NN);
    k_scan3<<<nScanB, 256, 0, stream>>>(deg, bsums, rowptr, NN);
    k_fill<<<(E + 255) / 256, 256, 0, stream>>>(ei, et, E, rowptr, fillc, pedge);

    int gemmBlocks = (NN + 63) / 64;
    dim3 wGrid(DIMX, N_REL + 1);
    int prepBlocks = (NN + 15) / 16;
    int gatherBlocks = ((size_t)NN * 64 + 255) / 256;

    // layer 1: y = emb @ [W1..W6] (bf16); out1 = emb @ root1 + bias1; gather adds means
    k_buildW2<<<wGrid, DIMX, 0, stream>>>(basis1, comp1, root1, W2);
    k_prepA<<<prepBlocks, 256, 0, stream>>>(node_emb, A2_l1, NN, 0);
    k_gemm_mfma<<<gemmBlocks, 256, 0, stream>>>(A2_l1, W2, bias1, y, out1, NN);
    k_gather<<<gatherBlocks, 256, 0, stream>>>(pedge, rowptr, invc, y, out1, NN);

    // layer 2: A = relu(out1), packed in place over out1
    k_buildW2<<<wGrid, DIMX, 0, stream>>>(basis2, comp2, root2, W2);
    k_prepA<<<prepBlocks, 256, 0, stream>>>(out1, A2_l2, NN, 1);
    k_gemm_mfma<<<gemmBlocks, 256, 0, stream>>>(A2_l2, W2, bias2, y, out2, NN);
    k_gather<<<gatherBlocks, 256, 0, stream>>>(pedge, rowptr, invc, y, out2, NN);

    // scorer (x2 = out2; hid aliases the now-dead y region)
    k_scorer_gemm<<<(P + BN - 1) / BN, 256, 0, stream>>>(out2, h_idx, p_idx, sw1, sb1, hid, P);
    k_scorer_out<<<((size_t)P * 32 + 255) / 256, 256, 0, stream>>>(hid, sw2, sb2, out, P);
}